// Round 1
// baseline (489.150 us; speedup 1.0000x reference)
//
#include <hip/hip_runtime.h>
#include <hip/hip_bf16.h>

#define NB 4096
#define MB 1024

typedef __bf16 bf16_t;
typedef __attribute__((ext_vector_type(8))) __bf16 bf16x8;
typedef __attribute__((ext_vector_type(4))) __bf16 bf16x4;
typedef __attribute__((ext_vector_type(4))) float f32x4;

// LDS tile layout: cells of 8 bf16 (16 B); cell index = kk*128 + r
//   kk = k-block (k/8) in [0,4), r = row in [0,128)
// MFMA 16x16x32 fragment: lane l reads 8 bf16 at (kk = l>>4, r = base + (l&15))

__device__ inline void stage_f32_tile(const float* __restrict__ src, int ld,
                                      int row0, int col0, bf16_t* lds, int tid) {
#pragma unroll
  for (int p = 0; p < 4; ++p) {
    int r = (tid >> 3) + p * 32;
    int c4 = tid & 7;  // float4 column index; col = c4*4
    const float4 v = *reinterpret_cast<const float4*>(
        src + (size_t)(row0 + r) * ld + col0 + c4 * 4);
    int kk = c4 >> 1, half = c4 & 1;
    bf16x4 b;
    b[0] = (bf16_t)v.x; b[1] = (bf16_t)v.y; b[2] = (bf16_t)v.z; b[3] = (bf16_t)v.w;
    *reinterpret_cast<bf16x4*>(lds + (size_t)(kk * 128 + r) * 8 + half * 4) = b;
  }
}

__device__ inline void stage_bf16_tile(const bf16_t* __restrict__ src, int ld,
                                       int row0, int col0, bf16_t* lds, int tid) {
#pragma unroll
  for (int p = 0; p < 2; ++p) {
    int r = (tid >> 2) + p * 64;
    int kk = tid & 3;
    bf16x8 v = *reinterpret_cast<const bf16x8*>(
        src + (size_t)(row0 + r) * ld + col0 + kk * 8);
    *reinterpret_cast<bf16x8*>(lds + (size_t)(kk * 128 + r) * 8) = v;
  }
}

// C[m,n] = sum_k A[m,k] * W[n,k]  (+ bias[n] when OUT_F32)
// A: MB x NB (f32 or bf16), W: NB x NB f32, C: MB x NB
template <bool A_BF16, bool OUT_F32>
__device__ inline void gemm_body(const void* __restrict__ Av,
                                 const float* __restrict__ W,
                                 const float* __restrict__ bias,
                                 void* __restrict__ Cv) {
  __shared__ bf16_t lA[4 * 128 * 8];
  __shared__ bf16_t lB[4 * 128 * 8];
  const int tid = threadIdx.x;
  const int lane = tid & 63, wave = tid >> 6;
  const int wm = (wave >> 1) * 64, wn = (wave & 1) * 64;  // 2x2 waves, 64x64 each
  const int row0 = blockIdx.y * 128, col0 = blockIdx.x * 128;
  const int lr = lane & 15, kk = lane >> 4;

  f32x4 acc[4][4] = {};

  for (int kt = 0; kt < NB; kt += 32) {
    if constexpr (A_BF16)
      stage_bf16_tile((const bf16_t*)Av, NB, row0, kt, lA, tid);
    else
      stage_f32_tile((const float*)Av, NB, row0, kt, lA, tid);
    stage_f32_tile(W, NB, col0, kt, lB, tid);
    __syncthreads();
    bf16x8 af[4], bg[4];
#pragma unroll
    for (int m = 0; m < 4; ++m)
      af[m] = *reinterpret_cast<const bf16x8*>(
          lA + (size_t)(kk * 128 + wm + m * 16 + lr) * 8);
#pragma unroll
    for (int n = 0; n < 4; ++n)
      bg[n] = *reinterpret_cast<const bf16x8*>(
          lB + (size_t)(kk * 128 + wn + n * 16 + lr) * 8);
#pragma unroll
    for (int m = 0; m < 4; ++m)
#pragma unroll
      for (int n = 0; n < 4; ++n)
        acc[m][n] = __builtin_amdgcn_mfma_f32_16x16x32_bf16(af[m], bg[n], acc[m][n], 0, 0, 0);
    __syncthreads();
  }

  // C/D layout: col = lane&15, row = (lane>>4)*4 + j
  const int fr = lane & 15, fq = lane >> 4;
#pragma unroll
  for (int m = 0; m < 4; ++m) {
#pragma unroll
    for (int n = 0; n < 4; ++n) {
#pragma unroll
      for (int j = 0; j < 4; ++j) {
        int r = row0 + wm + m * 16 + fq * 4 + j;
        int c = col0 + wn + n * 16 + fr;
        float v = acc[m][n][j];
        if constexpr (OUT_F32)
          ((float*)Cv)[(size_t)r * NB + c] = v + bias[c];
        else
          ((bf16_t*)Cv)[(size_t)r * NB + c] = (bf16_t)v;
      }
    }
  }
}

__global__ __launch_bounds__(256) void gemm1_kernel(const float* __restrict__ u,
                                                    const float* __restrict__ w,
                                                    const float* __restrict__ G,
                                                    const float* __restrict__ Bm,
                                                    bf16_t* __restrict__ T) {
  const size_t SZ = (size_t)MB * NB;
  int z = blockIdx.z;
  const float* A = (z & 1) ? w : u;
  const float* Wm = (z & 2) ? Bm : G;
  gemm_body<false, false>(A, Wm, nullptr, T + (size_t)z * SZ);
}

__global__ __launch_bounds__(256) void gemm2_kernel(const bf16_t* __restrict__ pq,
                                                    const float* __restrict__ Wp,
                                                    const float* __restrict__ Wq,
                                                    const float* __restrict__ bp,
                                                    const float* __restrict__ bq,
                                                    float* __restrict__ out) {
  const size_t SZ = (size_t)MB * NB;
  int z = blockIdx.z;
  gemm_body<true, true>(pq + (size_t)z * SZ, z ? Wq : Wp, z ? bq : bp,
                        out + (size_t)z * SZ);
}

// T: [Gu, Gw, Bu, Bw] each MB*NB bf16; writes p_mid, q_mid (bf16)
__global__ __launch_bounds__(256) void combine_kernel(
    const float* __restrict__ u, const float* __restrict__ w,
    const bf16_t* __restrict__ T, const float* __restrict__ bias_p,
    const float* __restrict__ bias_q, bf16_t* __restrict__ pq) {
  const size_t SZ = (size_t)MB * NB;
  size_t idx = ((size_t)blockIdx.x * blockDim.x + threadIdx.x) * 4;
  if (idx >= SZ) return;
  int c = (int)(idx & (NB - 1));
  float4 uu = *reinterpret_cast<const float4*>(u + idx);
  float4 ww = *reinterpret_cast<const float4*>(w + idx);
  bf16x4 gu = *reinterpret_cast<const bf16x4*>(T + idx);
  bf16x4 gw = *reinterpret_cast<const bf16x4*>(T + SZ + idx);
  bf16x4 bu = *reinterpret_cast<const bf16x4*>(T + 2 * SZ + idx);
  bf16x4 bw = *reinterpret_cast<const bf16x4*>(T + 3 * SZ + idx);
  float4 bp4 = *reinterpret_cast<const float4*>(bias_p + c);
  float4 bq4 = *reinterpret_cast<const float4*>(bias_q + c);
  bf16x4 po, qo;
#pragma unroll
  for (int e = 0; e < 4; ++e) {
    float U = (&uu.x)[e], Wv = (&ww.x)[e];
    float GU = (float)gu[e], GW = (float)gw[e];
    float BU = (float)bu[e], BW = (float)bw[e];
    float pv = U * GU + Wv * GW + Wv * BU - U * BW + (&bp4.x)[e];
    float qv = Wv * GU - U * GW - U * BU - Wv * BW + (&bq4.x)[e];
    po[e] = (bf16_t)pv;
    qo[e] = (bf16_t)qv;
  }
  *reinterpret_cast<bf16x4*>(pq + idx) = po;
  *reinterpret_cast<bf16x4*>(pq + SZ + idx) = qo;
}

extern "C" void kernel_launch(void* const* d_in, const int* in_sizes, int n_in,
                              void* d_out, int out_size, void* d_ws, size_t ws_size,
                              hipStream_t stream) {
  const float* u = (const float*)d_in[0];
  const float* w = (const float*)d_in[1];
  const float* G = (const float*)d_in[2];
  const float* Bm = (const float*)d_in[3];
  const float* bias_p = (const float*)d_in[4];
  const float* bias_q = (const float*)d_in[5];
  const float* Wp = (const float*)d_in[6];
  const float* bp = (const float*)d_in[7];
  const float* Wq = (const float*)d_in[8];
  const float* bq = (const float*)d_in[9];

  const size_t SZ = (size_t)MB * NB;
  bf16_t* T = (bf16_t*)d_ws;   // 4*SZ bf16: Gu, Gw, Bu, Bw
  bf16_t* pq = T + 4 * SZ;     // 2*SZ bf16: p_mid, q_mid
  (void)ws_size; (void)in_sizes; (void)n_in; (void)out_size;

  dim3 blk(256);
  gemm1_kernel<<<dim3(NB / 128, MB / 128, 4), blk, 0, stream>>>(u, w, G, Bm, T);
  combine_kernel<<<dim3((unsigned)(SZ / (256 * 4))), blk, 0, stream>>>(
      u, w, T, bias_p, bias_q, pq);
  gemm2_kernel<<<dim3(NB / 128, MB / 128, 2), blk, 0, stream>>>(
      pq, Wp, Wq, bp, bq, (float*)d_out);
}

// Round 2
// 401.440 us; speedup vs baseline: 1.2185x; 1.2185x over previous
//
#include <hip/hip_runtime.h>
#include <hip/hip_bf16.h>

#define NB 4096
#define MB 1024
#define SZ ((size_t)MB * NB)

typedef __bf16 bf16_t;
typedef __attribute__((ext_vector_type(8))) __bf16 bf16x8;
typedef __attribute__((ext_vector_type(4))) float f32x4;
typedef __attribute__((ext_vector_type(4))) unsigned int u32x4;

// LDS tile: 128 rows x 32 k (bf16), cells of 8 bf16 (16B).
// cell (r, kk) stored at bf16-offset r*32 + (kk ^ ((r>>1)&3))*8  [XOR swizzle,
// balances banks for both ds_write_b128 staging and ds_read_b128 frag reads]

__device__ __forceinline__ int swz_off(int r, int kk) {
  return r * 32 + ((kk ^ ((r >> 1) & 3)) << 3);
}

// stage one f32 tile (128 rows from row0, k-cols k0..k0+31) into swizzled LDS;
// one 16B cell per thread index t in [0,512)
__device__ __forceinline__ void stage_f32(const float* __restrict__ src,
                                          int row0, int k0, bf16_t* lds, int t) {
  int r = t >> 2, kk = t & 3;
  const float* p = src + (size_t)(row0 + r) * NB + k0 + (kk << 3);
  float4 v0 = *reinterpret_cast<const float4*>(p);
  float4 v1 = *reinterpret_cast<const float4*>(p + 4);
  bf16x8 b;
  b[0] = (bf16_t)v0.x; b[1] = (bf16_t)v0.y; b[2] = (bf16_t)v0.z; b[3] = (bf16_t)v0.w;
  b[4] = (bf16_t)v1.x; b[5] = (bf16_t)v1.y; b[6] = (bf16_t)v1.z; b[7] = (bf16_t)v1.w;
  *reinterpret_cast<bf16x8*>(lds + swz_off(r, kk)) = b;
}

__device__ __forceinline__ bf16x8 neg8(bf16x8 x) {
  u32x4 t;
  __builtin_memcpy(&t, &x, 16);
  t ^= 0x80008000u;
  bf16x8 y;
  __builtin_memcpy(&y, &t, 16);
  return y;
}

// Fused stage 1: S = u@G^T - w@B^T, T = w@G^T + u@B^T, then
// p_mid = u*S + w*T + bias_p, q_mid = w*S - u*T + bias_q  (bf16 to ws)
// 512 threads, 8 waves (2m x 4n), per-wave 64x32, block tile 128x128.
__global__ __launch_bounds__(512, 2) void fused1_kernel(
    const float* __restrict__ u, const float* __restrict__ w,
    const float* __restrict__ G, const float* __restrict__ Bm,
    const float* __restrict__ bias_p, const float* __restrict__ bias_q,
    bf16_t* __restrict__ pq) {
  __shared__ bf16_t lU[128 * 32], lW[128 * 32], lG[128 * 32], lB[128 * 32];
  const int tid = threadIdx.x;
  const int lane = tid & 63, wv = tid >> 6;
  const int wm = (wv >> 2) * 64, wn = (wv & 3) * 32;
  const int row0 = blockIdx.y * 128, col0 = blockIdx.x * 128;
  const int lr = lane & 15, kq = lane >> 4;
  const int fslot = (kq ^ ((lr >> 1) & 3)) << 3;  // swizzled frag slot (bf16 units)

  f32x4 aS[4][2] = {};
  f32x4 aT[4][2] = {};

  for (int kt = 0; kt < NB; kt += 32) {
    stage_f32(u, row0, kt, lU, tid);
    stage_f32(w, row0, kt, lW, tid);
    stage_f32(G, col0, kt, lG, tid);
    stage_f32(Bm, col0, kt, lB, tid);
    __syncthreads();
    bf16x8 au[4], aw[4], bG[2], bB[2], bBn[2];
#pragma unroll
    for (int m = 0; m < 4; ++m) {
      int off = (wm + m * 16 + lr) * 32 + fslot;
      au[m] = *reinterpret_cast<const bf16x8*>(lU + off);
      aw[m] = *reinterpret_cast<const bf16x8*>(lW + off);
    }
#pragma unroll
    for (int n = 0; n < 2; ++n) {
      int off = (wn + n * 16 + lr) * 32 + fslot;
      bG[n] = *reinterpret_cast<const bf16x8*>(lG + off);
      bB[n] = *reinterpret_cast<const bf16x8*>(lB + off);
      bBn[n] = neg8(bB[n]);
    }
#pragma unroll
    for (int m = 0; m < 4; ++m)
#pragma unroll
      for (int n = 0; n < 2; ++n) {
        aS[m][n] = __builtin_amdgcn_mfma_f32_16x16x32_bf16(au[m], bG[n], aS[m][n], 0, 0, 0);
        aS[m][n] = __builtin_amdgcn_mfma_f32_16x16x32_bf16(aw[m], bBn[n], aS[m][n], 0, 0, 0);
        aT[m][n] = __builtin_amdgcn_mfma_f32_16x16x32_bf16(aw[m], bG[n], aT[m][n], 0, 0, 0);
        aT[m][n] = __builtin_amdgcn_mfma_f32_16x16x32_bf16(au[m], bB[n], aT[m][n], 0, 0, 0);
      }
    __syncthreads();
  }

  // epilogue: combine with u,w (re-read, LLC-resident) + biases, write bf16
  const int fr = lane & 15, fq = lane >> 4;
#pragma unroll
  for (int m = 0; m < 4; ++m)
#pragma unroll
    for (int n = 0; n < 2; ++n) {
#pragma unroll
      for (int j = 0; j < 4; ++j) {
        int r = row0 + wm + m * 16 + fq * 4 + j;
        int c = col0 + wn + n * 16 + fr;
        size_t idx = (size_t)r * NB + c;
        float U = u[idx], W = w[idx];
        float S = aS[m][n][j], T = aT[m][n][j];
        pq[idx] = (bf16_t)(U * S + W * T + bias_p[c]);
        pq[SZ + idx] = (bf16_t)(W * S - U * T + bias_q[c]);
      }
    }
}

// Stage 2: out_z = pq_z @ W_z^T + b_z (f32 out). 256 threads, 4 waves 2x2,
// per-wave 64x64. A (bf16) via global_load_lds w/ pre-swizzled source.
__global__ __launch_bounds__(256, 2) void gemm2_kernel(
    const bf16_t* __restrict__ pq, const float* __restrict__ Wp,
    const float* __restrict__ Wq, const float* __restrict__ bp,
    const float* __restrict__ bq, float* __restrict__ out) {
  __shared__ bf16_t lA[128 * 32], lW[128 * 32];
  const int z = blockIdx.z;
  const bf16_t* A = pq + (size_t)z * SZ;
  const float* Wm = z ? Wq : Wp;
  const float* bias = z ? bq : bp;
  float* C = out + (size_t)z * SZ;
  const int tid = threadIdx.x;
  const int lane = tid & 63, wv = tid >> 6;
  const int wm = (wv >> 1) * 64, wn = (wv & 1) * 64;
  const int row0 = blockIdx.y * 128, col0 = blockIdx.x * 128;
  const int lr = lane & 15, kq = lane >> 4;
  const int fslot = (kq ^ ((lr >> 1) & 3)) << 3;

  f32x4 acc[4][4] = {};

  for (int kt = 0; kt < NB; kt += 32) {
    // A: 2 cells per thread via global_load_lds (linear LDS dest, source
    // address pre-swizzled so swizzled reads see logical layout)
#pragma unroll
    for (int p = 0; p < 2; ++p) {
      int cb = p * 256 + wv * 64;  // wave-uniform base cell
      int ci = cb + lane;
      int r = ci >> 2, kl = ci & 3;
      int ks = kl ^ ((r >> 1) & 3);
      const bf16_t* g = A + (size_t)(row0 + r) * NB + kt + (ks << 3);
      __builtin_amdgcn_global_load_lds(
          (const __attribute__((address_space(1))) unsigned int*)g,
          (__attribute__((address_space(3))) unsigned int*)(lA + cb * 8),
          16, 0, 0);
    }
    // W: f32 -> bf16 reg-staged, 2 cells per thread
#pragma unroll
    for (int p = 0; p < 2; ++p)
      stage_f32(Wm, col0, kt, lW, p * 256 + tid);
    __syncthreads();
    bf16x8 af[4], bg[4];
#pragma unroll
    for (int m = 0; m < 4; ++m)
      af[m] = *reinterpret_cast<const bf16x8*>(lA + (wm + m * 16 + lr) * 32 + fslot);
#pragma unroll
    for (int n = 0; n < 4; ++n)
      bg[n] = *reinterpret_cast<const bf16x8*>(lW + (wn + n * 16 + lr) * 32 + fslot);
#pragma unroll
    for (int m = 0; m < 4; ++m)
#pragma unroll
      for (int n = 0; n < 4; ++n)
        acc[m][n] = __builtin_amdgcn_mfma_f32_16x16x32_bf16(af[m], bg[n], acc[m][n], 0, 0, 0);
    __syncthreads();
  }

  const int fr = lane & 15, fq = lane >> 4;
#pragma unroll
  for (int m = 0; m < 4; ++m)
#pragma unroll
    for (int n = 0; n < 4; ++n)
#pragma unroll
      for (int j = 0; j < 4; ++j) {
        int r = row0 + wm + m * 16 + fq * 4 + j;
        int c = col0 + wn + n * 16 + fr;
        C[(size_t)r * NB + c] = acc[m][n][j] + bias[c];
      }
}

extern "C" void kernel_launch(void* const* d_in, const int* in_sizes, int n_in,
                              void* d_out, int out_size, void* d_ws, size_t ws_size,
                              hipStream_t stream) {
  const float* u = (const float*)d_in[0];
  const float* w = (const float*)d_in[1];
  const float* G = (const float*)d_in[2];
  const float* Bm = (const float*)d_in[3];
  const float* bias_p = (const float*)d_in[4];
  const float* bias_q = (const float*)d_in[5];
  const float* Wp = (const float*)d_in[6];
  const float* bp = (const float*)d_in[7];
  const float* Wq = (const float*)d_in[8];
  const float* bq = (const float*)d_in[9];
  (void)in_sizes; (void)n_in; (void)out_size; (void)ws_size;

  bf16_t* pqw = (bf16_t*)d_ws;  // p_mid, q_mid: 2*SZ bf16 = 16 MB

  fused1_kernel<<<dim3(NB / 128, MB / 128), 512, 0, stream>>>(
      u, w, G, Bm, bias_p, bias_q, pqw);
  gemm2_kernel<<<dim3(NB / 128, MB / 128, 2), 256, 0, stream>>>(
      pqw, Wp, Wq, bp, bq, (float*)d_out);
}

// Round 3
// 377.315 us; speedup vs baseline: 1.2964x; 1.0639x over previous
//
#include <hip/hip_runtime.h>
#include <hip/hip_bf16.h>

#define NB 4096
#define MB 1024
#define SZ ((size_t)MB * NB)
#define NN ((size_t)NB * NB)

typedef __bf16 bf16_t;
typedef __attribute__((ext_vector_type(8))) __bf16 bf16x8;
typedef __attribute__((ext_vector_type(4))) __bf16 bf16x4;
typedef __attribute__((ext_vector_type(4))) float f32x4;
typedef __attribute__((ext_vector_type(4))) unsigned int u32x4;

// LDS tile: R rows x 32 k (bf16), cells of 8 bf16 (16B).
// cell (r, kk) at bf16-offset r*32 + (kk ^ ((r>>1)&3))*8  (XOR swizzle)
__device__ __forceinline__ int swz_off(int r, int kk) {
  return r * 32 + ((kk ^ ((r >> 1) & 3)) << 3);
}

__device__ __forceinline__ bf16x8 neg8(bf16x8 x) {
  u32x4 t;
  __builtin_memcpy(&t, &x, 16);
  t ^= 0x80008000u;
  bf16x8 y;
  __builtin_memcpy(&y, &t, 16);
  return y;
}

__device__ __forceinline__ bf16x8 cvt8(float4 a, float4 b) {
  bf16x8 v;
  v[0] = (bf16_t)a.x; v[1] = (bf16_t)a.y; v[2] = (bf16_t)a.z; v[3] = (bf16_t)a.w;
  v[4] = (bf16_t)b.x; v[5] = (bf16_t)b.y; v[6] = (bf16_t)b.z; v[7] = (bf16_t)b.w;
  return v;
}

// ---------------- prep: f32 -> bf16 for u, w, G, B ----------------
#define ITEM_S (SZ / 8)
#define ITEM_N (NN / 8)
#define ITEM_TOT (2 * ITEM_S + 2 * ITEM_N)

__global__ __launch_bounds__(256) void prep_kernel(
    const float* __restrict__ u, const float* __restrict__ w,
    const float* __restrict__ G, const float* __restrict__ Bm,
    bf16_t* __restrict__ ws) {
  size_t stride = (size_t)gridDim.x * blockDim.x;
  for (size_t i = (size_t)blockIdx.x * blockDim.x + threadIdx.x; i < ITEM_TOT;
       i += stride) {
    const float* src;
    bf16_t* dst;
    size_t off;
    if (i < ITEM_S) { src = u; dst = ws; off = i; }
    else if (i < 2 * ITEM_S) { src = w; dst = ws + SZ; off = i - ITEM_S; }
    else if (i < 2 * ITEM_S + ITEM_N) { src = G; dst = ws + 2 * SZ; off = i - 2 * ITEM_S; }
    else { src = Bm; dst = ws + 2 * SZ + NN; off = i - 2 * ITEM_S - ITEM_N; }
    const float4* s = reinterpret_cast<const float4*>(src) + off * 2;
    float4 a = s[0], b = s[1];
    reinterpret_cast<bf16x8*>(dst)[off] = cvt8(a, b);
  }
}

// ---------------- fused stage 1 (bf16 inputs, gload_lds, dbuf) ----------------
// S = u@G^T - w@B^T, T = w@G^T + u@B^T; p_mid = u*S + w*T + bias_p,
// q_mid = w*S - u*T + bias_q (bf16). Tile 64x64, 256 thr, 4 waves 2x2.
__global__ __launch_bounds__(256, 4) void fused1_v2(
    const float* __restrict__ u, const float* __restrict__ w,
    const bf16_t* __restrict__ ubf, const bf16_t* __restrict__ wbf,
    const bf16_t* __restrict__ Gbf, const bf16_t* __restrict__ Bbf,
    const float* __restrict__ bias_p, const float* __restrict__ bias_q,
    bf16_t* __restrict__ pq) {
  __shared__ bf16_t lds[2][4][64 * 32];
  const int tid = threadIdx.x, lane = tid & 63, wv = tid >> 6;
  const int bx = blockIdx.x;
  const int row0 = (bx >> 6) * 64, col0 = (bx & 63) * 64;
  const int wm = (wv >> 1) * 32, wn = (wv & 1) * 32;
  const int lr = lane & 15, kq = lane >> 4;
  const int fslot = (kq ^ ((lr >> 1) & 3)) << 3;

  // staging: 1 cell (16B) per thread per tile; pre-swizzled global source
  const int sr = tid >> 2, skl = tid & 3;
  const int sks = skl ^ ((sr >> 1) & 3);
  const bf16_t* gsrc[4];
  gsrc[0] = ubf + (size_t)(row0 + sr) * NB + (sks << 3);
  gsrc[1] = wbf + (size_t)(row0 + sr) * NB + (sks << 3);
  gsrc[2] = Gbf + (size_t)(col0 + sr) * NB + (sks << 3);
  gsrc[3] = Bbf + (size_t)(col0 + sr) * NB + (sks << 3);
  const int ldsbase = wv * 512;  // wave-uniform dest (bf16 units)

  f32x4 aS[2][2] = {}, aT[2][2] = {};

#define STAGE1(buf, kt)                                                        \
  {                                                                            \
    _Pragma("unroll") for (int t = 0; t < 4; ++t)                              \
        __builtin_amdgcn_global_load_lds(                                      \
            (const __attribute__((address_space(1))) unsigned int*)(gsrc[t] +  \
                                                                    (kt)),     \
            (__attribute__((address_space(3))) unsigned int*)(&lds[buf][t]     \
                                                                  [ldsbase]),  \
            16, 0, 0);                                                         \
  }

  STAGE1(0, 0);
  __syncthreads();

  int cur = 0;
  for (int kt = 0; kt < NB; kt += 32) {
    if (kt + 32 < NB) STAGE1(cur ^ 1, kt + 32);
    bf16x8 au[2], aw[2], bG[2], bB[2];
#pragma unroll
    for (int m = 0; m < 2; ++m) {
      int off = (wm + m * 16 + lr) * 32 + fslot;
      au[m] = *reinterpret_cast<const bf16x8*>(&lds[cur][0][off]);
      aw[m] = *reinterpret_cast<const bf16x8*>(&lds[cur][1][off]);
    }
#pragma unroll
    for (int n = 0; n < 2; ++n) {
      int off = (wn + n * 16 + lr) * 32 + fslot;
      bG[n] = *reinterpret_cast<const bf16x8*>(&lds[cur][2][off]);
      bB[n] = *reinterpret_cast<const bf16x8*>(&lds[cur][3][off]);
    }
#pragma unroll
    for (int m = 0; m < 2; ++m)
#pragma unroll
      for (int n = 0; n < 2; ++n) {
        bf16x8 bn = neg8(bB[n]);
        aS[m][n] = __builtin_amdgcn_mfma_f32_16x16x32_bf16(au[m], bG[n], aS[m][n], 0, 0, 0);
        aS[m][n] = __builtin_amdgcn_mfma_f32_16x16x32_bf16(aw[m], bn, aS[m][n], 0, 0, 0);
        aT[m][n] = __builtin_amdgcn_mfma_f32_16x16x32_bf16(aw[m], bG[n], aT[m][n], 0, 0, 0);
        aT[m][n] = __builtin_amdgcn_mfma_f32_16x16x32_bf16(au[m], bB[n], aT[m][n], 0, 0, 0);
      }
    __syncthreads();
    cur ^= 1;
  }

  const int fr = lane & 15, fq = lane >> 4;
#pragma unroll
  for (int m = 0; m < 2; ++m)
#pragma unroll
    for (int n = 0; n < 2; ++n)
#pragma unroll
      for (int j = 0; j < 4; ++j) {
        int r = row0 + wm + m * 16 + fq * 4 + j;
        int c = col0 + wn + n * 16 + fr;
        size_t idx = (size_t)r * NB + c;
        float U = u[idx], W = w[idx];
        float S = aS[m][n][j], T = aT[m][n][j];
        pq[idx] = (bf16_t)(U * S + W * T + bias_p[c]);
        pq[SZ + idx] = (bf16_t)(W * S - U * T + bias_q[c]);
      }
}

// ---------------- stage 2: out_z = pq_z @ W_z^T + b_z, dbuf ----------------
__global__ __launch_bounds__(256, 2) void gemm2_v2(
    const bf16_t* __restrict__ pq, const float* __restrict__ Wp,
    const float* __restrict__ Wq, const float* __restrict__ bp,
    const float* __restrict__ bq, float* __restrict__ out) {
  __shared__ bf16_t lA[2][128 * 32], lW[2][128 * 32];
  const int z = blockIdx.z;
  const bf16_t* A = pq + (size_t)z * SZ;
  const float* Wm = z ? Wq : Wp;
  const float* bias = z ? bq : bp;
  float* C = out + (size_t)z * SZ;
  const int tid = threadIdx.x, lane = tid & 63, wv = tid >> 6;
  const int wm = (wv >> 1) * 64, wn = (wv & 1) * 64;
  const int row0 = blockIdx.y * 128, col0 = blockIdx.x * 128;
  const int lr = lane & 15, kq = lane >> 4;
  const int fslot = (kq ^ ((lr >> 1) & 3)) << 3;

  f32x4 acc[4][4] = {};

  // A staging (gload_lds, pre-swizzled source): 2 cells per thread
  const bf16_t* gA[2];
  int cbase[2];
#pragma unroll
  for (int p = 0; p < 2; ++p) {
    int cb = p * 256 + wv * 64;
    cbase[p] = cb;
    int ci = cb + lane;
    int r = ci >> 2, kl = ci & 3;
    int ks = kl ^ ((r >> 1) & 3);
    gA[p] = A + (size_t)(row0 + r) * NB + (ks << 3);
  }
  // W staging (reg-staged f32->bf16): 2 cells per thread
  const float* gW[2];
  int wro[2], wko[2];
#pragma unroll
  for (int p = 0; p < 2; ++p) {
    int ci = p * 256 + tid;
    int r = ci >> 2, kl = ci & 3;
    wro[p] = r; wko[p] = kl;
    gW[p] = Wm + (size_t)(col0 + r) * NB + (kl << 3);
  }

#define STAGEA(buf, kt)                                                        \
  {                                                                            \
    _Pragma("unroll") for (int p = 0; p < 2; ++p)                              \
        __builtin_amdgcn_global_load_lds(                                      \
            (const __attribute__((address_space(1))) unsigned int*)(gA[p] +    \
                                                                    (kt)),     \
            (__attribute__((address_space(3))) unsigned int*)(&lA[buf]         \
                                                                 [cbase[p] *   \
                                                                  8]),         \
            16, 0, 0);                                                         \
  }

  // prologue
  STAGEA(0, 0);
  {
#pragma unroll
    for (int p = 0; p < 2; ++p) {
      float4 a = *reinterpret_cast<const float4*>(gW[p]);
      float4 b = *reinterpret_cast<const float4*>(gW[p] + 4);
      *reinterpret_cast<bf16x8*>(&lW[0][swz_off(wro[p], wko[p])]) = cvt8(a, b);
    }
  }
  __syncthreads();

  int cur = 0;
  for (int kt = 0; kt < NB; kt += 32) {
    const bool nx = (kt + 32 < NB);
    float4 wa[2], wb[2];
    if (nx) {
      STAGEA(cur ^ 1, kt + 32);
#pragma unroll
      for (int p = 0; p < 2; ++p) {
        wa[p] = *reinterpret_cast<const float4*>(gW[p] + kt + 32);
        wb[p] = *reinterpret_cast<const float4*>(gW[p] + kt + 36);
      }
    }
    bf16x8 af[4], bg[4];
#pragma unroll
    for (int m = 0; m < 4; ++m)
      af[m] = *reinterpret_cast<const bf16x8*>(&lA[cur][(wm + m * 16 + lr) * 32 + fslot]);
#pragma unroll
    for (int n = 0; n < 4; ++n)
      bg[n] = *reinterpret_cast<const bf16x8*>(&lW[cur][(wn + n * 16 + lr) * 32 + fslot]);
#pragma unroll
    for (int m = 0; m < 4; ++m)
#pragma unroll
      for (int n = 0; n < 4; ++n)
        acc[m][n] = __builtin_amdgcn_mfma_f32_16x16x32_bf16(af[m], bg[n], acc[m][n], 0, 0, 0);
    if (nx) {
#pragma unroll
      for (int p = 0; p < 2; ++p)
        *reinterpret_cast<bf16x8*>(&lW[cur ^ 1][swz_off(wro[p], wko[p])]) = cvt8(wa[p], wb[p]);
    }
    __syncthreads();
    cur ^= 1;
  }

  const int fr = lane & 15, fq = lane >> 4;
#pragma unroll
  for (int m = 0; m < 4; ++m)
#pragma unroll
    for (int n = 0; n < 4; ++n)
#pragma unroll
      for (int j = 0; j < 4; ++j) {
        int r = row0 + wm + m * 16 + fq * 4 + j;
        int c = col0 + wn + n * 16 + fr;
        C[(size_t)r * NB + c] = acc[m][n][j] + bias[c];
      }
}

// ---------------- fallback path (round-2, for small ws) ----------------
__device__ __forceinline__ void fb_stage_f32(const float* __restrict__ src,
                                             int row0, int k0, bf16_t* lds, int t) {
  int r = t >> 2, kk = t & 3;
  const float* p = src + (size_t)(row0 + r) * NB + k0 + (kk << 3);
  float4 v0 = *reinterpret_cast<const float4*>(p);
  float4 v1 = *reinterpret_cast<const float4*>(p + 4);
  *reinterpret_cast<bf16x8*>(lds + swz_off(r, kk)) = cvt8(v0, v1);
}

__global__ __launch_bounds__(512, 2) void fb_fused1(
    const float* __restrict__ u, const float* __restrict__ w,
    const float* __restrict__ G, const float* __restrict__ Bm,
    const float* __restrict__ bias_p, const float* __restrict__ bias_q,
    bf16_t* __restrict__ pq) {
  __shared__ bf16_t lU[128 * 32], lW[128 * 32], lG[128 * 32], lB[128 * 32];
  const int tid = threadIdx.x;
  const int lane = tid & 63, wv = tid >> 6;
  const int wm = (wv >> 2) * 64, wn = (wv & 3) * 32;
  const int row0 = blockIdx.y * 128, col0 = blockIdx.x * 128;
  const int lr = lane & 15, kq = lane >> 4;
  const int fslot = (kq ^ ((lr >> 1) & 3)) << 3;
  f32x4 aS[4][2] = {}, aT[4][2] = {};
  for (int kt = 0; kt < NB; kt += 32) {
    fb_stage_f32(u, row0, kt, lU, tid);
    fb_stage_f32(w, row0, kt, lW, tid);
    fb_stage_f32(G, col0, kt, lG, tid);
    fb_stage_f32(Bm, col0, kt, lB, tid);
    __syncthreads();
    bf16x8 au[4], aw[4], bG[2], bB[2], bBn[2];
#pragma unroll
    for (int m = 0; m < 4; ++m) {
      int off = (wm + m * 16 + lr) * 32 + fslot;
      au[m] = *reinterpret_cast<const bf16x8*>(lU + off);
      aw[m] = *reinterpret_cast<const bf16x8*>(lW + off);
    }
#pragma unroll
    for (int n = 0; n < 2; ++n) {
      int off = (wn + n * 16 + lr) * 32 + fslot;
      bG[n] = *reinterpret_cast<const bf16x8*>(lG + off);
      bB[n] = *reinterpret_cast<const bf16x8*>(lB + off);
      bBn[n] = neg8(bB[n]);
    }
#pragma unroll
    for (int m = 0; m < 4; ++m)
#pragma unroll
      for (int n = 0; n < 2; ++n) {
        aS[m][n] = __builtin_amdgcn_mfma_f32_16x16x32_bf16(au[m], bG[n], aS[m][n], 0, 0, 0);
        aS[m][n] = __builtin_amdgcn_mfma_f32_16x16x32_bf16(aw[m], bBn[n], aS[m][n], 0, 0, 0);
        aT[m][n] = __builtin_amdgcn_mfma_f32_16x16x32_bf16(aw[m], bG[n], aT[m][n], 0, 0, 0);
        aT[m][n] = __builtin_amdgcn_mfma_f32_16x16x32_bf16(au[m], bB[n], aT[m][n], 0, 0, 0);
      }
    __syncthreads();
  }
  const int fr = lane & 15, fq = lane >> 4;
#pragma unroll
  for (int m = 0; m < 4; ++m)
#pragma unroll
    for (int n = 0; n < 2; ++n)
#pragma unroll
      for (int j = 0; j < 4; ++j) {
        int r = row0 + wm + m * 16 + fq * 4 + j;
        int c = col0 + wn + n * 16 + fr;
        size_t idx = (size_t)r * NB + c;
        float U = u[idx], W = w[idx];
        float S = aS[m][n][j], T = aT[m][n][j];
        pq[idx] = (bf16_t)(U * S + W * T + bias_p[c]);
        pq[SZ + idx] = (bf16_t)(W * S - U * T + bias_q[c]);
      }
}

__global__ __launch_bounds__(256, 2) void fb_gemm2(
    const bf16_t* __restrict__ pq, const float* __restrict__ Wp,
    const float* __restrict__ Wq, const float* __restrict__ bp,
    const float* __restrict__ bq, float* __restrict__ out) {
  __shared__ bf16_t lA[128 * 32], lW[128 * 32];
  const int z = blockIdx.z;
  const bf16_t* A = pq + (size_t)z * SZ;
  const float* Wm = z ? Wq : Wp;
  const float* bias = z ? bq : bp;
  float* C = out + (size_t)z * SZ;
  const int tid = threadIdx.x;
  const int lane = tid & 63, wv = tid >> 6;
  const int wm = (wv >> 1) * 64, wn = (wv & 1) * 64;
  const int row0 = blockIdx.y * 128, col0 = blockIdx.x * 128;
  const int lr = lane & 15, kq = lane >> 4;
  const int fslot = (kq ^ ((lr >> 1) & 3)) << 3;
  f32x4 acc[4][4] = {};
  for (int kt = 0; kt < NB; kt += 32) {
#pragma unroll
    for (int p = 0; p < 2; ++p) {
      int cb = p * 256 + wv * 64;
      int ci = cb + lane;
      int r = ci >> 2, kl = ci & 3;
      int ks = kl ^ ((r >> 1) & 3);
      const bf16_t* g = A + (size_t)(row0 + r) * NB + kt + (ks << 3);
      __builtin_amdgcn_global_load_lds(
          (const __attribute__((address_space(1))) unsigned int*)g,
          (__attribute__((address_space(3))) unsigned int*)(lA + cb * 8),
          16, 0, 0);
    }
#pragma unroll
    for (int p = 0; p < 2; ++p)
      fb_stage_f32(Wm, col0, kt, lW, p * 256 + tid);
    __syncthreads();
    bf16x8 af[4], bg[4];
#pragma unroll
    for (int m = 0; m < 4; ++m)
      af[m] = *reinterpret_cast<const bf16x8*>(lA + (wm + m * 16 + lr) * 32 + fslot);
#pragma unroll
    for (int n = 0; n < 4; ++n)
      bg[n] = *reinterpret_cast<const bf16x8*>(lW + (wn + n * 16 + lr) * 32 + fslot);
#pragma unroll
    for (int m = 0; m < 4; ++m)
#pragma unroll
      for (int n = 0; n < 4; ++n)
        acc[m][n] = __builtin_amdgcn_mfma_f32_16x16x32_bf16(af[m], bg[n], acc[m][n], 0, 0, 0);
    __syncthreads();
  }
  const int fr = lane & 15, fq = lane >> 4;
#pragma unroll
  for (int m = 0; m < 4; ++m)
#pragma unroll
    for (int n = 0; n < 4; ++n)
#pragma unroll
      for (int j = 0; j < 4; ++j) {
        int r = row0 + wm + m * 16 + fq * 4 + j;
        int c = col0 + wn + n * 16 + fr;
        C[(size_t)r * NB + c] = acc[m][n][j] + bias[c];
      }
}

extern "C" void kernel_launch(void* const* d_in, const int* in_sizes, int n_in,
                              void* d_out, int out_size, void* d_ws, size_t ws_size,
                              hipStream_t stream) {
  const float* u = (const float*)d_in[0];
  const float* w = (const float*)d_in[1];
  const float* G = (const float*)d_in[2];
  const float* Bm = (const float*)d_in[3];
  const float* bias_p = (const float*)d_in[4];
  const float* bias_q = (const float*)d_in[5];
  const float* Wp = (const float*)d_in[6];
  const float* bp = (const float*)d_in[7];
  const float* Wq = (const float*)d_in[8];
  const float* bq = (const float*)d_in[9];
  (void)in_sizes; (void)n_in; (void)out_size;

  const size_t need = (4 * SZ + 2 * NN) * sizeof(bf16_t);
  if (ws_size >= need) {
    bf16_t* ws = (bf16_t*)d_ws;
    bf16_t* ubf = ws;
    bf16_t* wbf = ws + SZ;
    bf16_t* Gbf = ws + 2 * SZ;
    bf16_t* Bbf = Gbf + NN;
    bf16_t* pqw = Bbf + NN;
    prep_kernel<<<2048, 256, 0, stream>>>(u, w, G, Bm, ws);
    fused1_v2<<<1024, 256, 0, stream>>>(u, w, ubf, wbf, Gbf, Bbf,
                                        bias_p, bias_q, pqw);
    gemm2_v2<<<dim3(32, 8, 2), 256, 0, stream>>>(pqw, Wp, Wq, bp, bq,
                                                 (float*)d_out);
  } else {
    bf16_t* pqw = (bf16_t*)d_ws;
    fb_fused1<<<dim3(NB / 128, MB / 128), 512, 0, stream>>>(
        u, w, G, Bm, bias_p, bias_q, pqw);
    fb_gemm2<<<dim3(NB / 128, MB / 128, 2), 256, 0, stream>>>(
        pqw, Wp, Wq, bp, bq, (float*)d_out);
  }
}

// Round 4
// 369.890 us; speedup vs baseline: 1.3224x; 1.0201x over previous
//
#include <hip/hip_runtime.h>
#include <hip/hip_bf16.h>

#define NB 4096
#define MB 1024
#define SZ ((size_t)MB * NB)
#define NN ((size_t)NB * NB)

typedef __bf16 bf16_t;
typedef __attribute__((ext_vector_type(8))) __bf16 bf16x8;
typedef __attribute__((ext_vector_type(4))) float f32x4;
typedef __attribute__((ext_vector_type(4))) unsigned int u32x4;

// LDS tile: R rows x 32 k (bf16), cells of 8 bf16 (16B).
// cell (r, kk) at bf16-offset r*32 + (kk ^ ((r>>1)&3))*8  (XOR swizzle)
__device__ __forceinline__ int swz_off(int r, int kk) {
  return r * 32 + ((kk ^ ((r >> 1) & 3)) << 3);
}

__device__ __forceinline__ bf16x8 neg8(bf16x8 x) {
  u32x4 t;
  __builtin_memcpy(&t, &x, 16);
  t ^= 0x80008000u;
  bf16x8 y;
  __builtin_memcpy(&y, &t, 16);
  return y;
}

__device__ __forceinline__ bf16x8 cvt8(float4 a, float4 b) {
  bf16x8 v;
  v[0] = (bf16_t)a.x; v[1] = (bf16_t)a.y; v[2] = (bf16_t)a.z; v[3] = (bf16_t)a.w;
  v[4] = (bf16_t)b.x; v[5] = (bf16_t)b.y; v[6] = (bf16_t)b.z; v[7] = (bf16_t)b.w;
  return v;
}

// ---------------- prep: f32 -> bf16 ----------------
#define ITEM_S (SZ / 8)
#define ITEM_N (NN / 8)

// 6-array variant: u, w, G, B, Wp, Wq
__global__ __launch_bounds__(256) void prep6_kernel(
    const float* __restrict__ u, const float* __restrict__ w,
    const float* __restrict__ G, const float* __restrict__ Bm,
    const float* __restrict__ Wp, const float* __restrict__ Wq,
    bf16_t* __restrict__ ws) {
  size_t stride = (size_t)gridDim.x * blockDim.x;
  const size_t tot = 2 * ITEM_S + 4 * ITEM_N;
  for (size_t i = (size_t)blockIdx.x * blockDim.x + threadIdx.x; i < tot;
       i += stride) {
    const float* src;
    bf16_t* dst;
    size_t off;
    if (i < ITEM_S) { src = u; dst = ws; off = i; }
    else if (i < 2 * ITEM_S) { src = w; dst = ws + SZ; off = i - ITEM_S; }
    else if (i < 2 * ITEM_S + ITEM_N) { src = G; dst = ws + 2 * SZ; off = i - 2 * ITEM_S; }
    else if (i < 2 * ITEM_S + 2 * ITEM_N) { src = Bm; dst = ws + 2 * SZ + NN; off = i - 2 * ITEM_S - ITEM_N; }
    else if (i < 2 * ITEM_S + 3 * ITEM_N) { src = Wp; dst = ws + 2 * SZ + 2 * NN; off = i - 2 * ITEM_S - 2 * ITEM_N; }
    else { src = Wq; dst = ws + 2 * SZ + 3 * NN; off = i - 2 * ITEM_S - 3 * ITEM_N; }
    const float4* s = reinterpret_cast<const float4*>(src) + off * 2;
    reinterpret_cast<bf16x8*>(dst)[off] = cvt8(s[0], s[1]);
  }
}

// 4-array variant (middle fallback): u, w, G, B
__global__ __launch_bounds__(256) void prep4_kernel(
    const float* __restrict__ u, const float* __restrict__ w,
    const float* __restrict__ G, const float* __restrict__ Bm,
    bf16_t* __restrict__ ws) {
  size_t stride = (size_t)gridDim.x * blockDim.x;
  const size_t tot = 2 * ITEM_S + 2 * ITEM_N;
  for (size_t i = (size_t)blockIdx.x * blockDim.x + threadIdx.x; i < tot;
       i += stride) {
    const float* src;
    bf16_t* dst;
    size_t off;
    if (i < ITEM_S) { src = u; dst = ws; off = i; }
    else if (i < 2 * ITEM_S) { src = w; dst = ws + SZ; off = i - ITEM_S; }
    else if (i < 2 * ITEM_S + ITEM_N) { src = G; dst = ws + 2 * SZ; off = i - 2 * ITEM_S; }
    else { src = Bm; dst = ws + 2 * SZ + NN; off = i - 2 * ITEM_S - ITEM_N; }
    const float4* s = reinterpret_cast<const float4*>(src) + off * 2;
    reinterpret_cast<bf16x8*>(dst)[off] = cvt8(s[0], s[1]);
  }
}

// ---------------- fused stage 1 (bf16 inputs, gload_lds, dbuf) ----------------
// S = u@G^T - w@B^T, T = w@G^T + u@B^T; p_mid = u*S + w*T + bias_p,
// q_mid = w*S - u*T + bias_q (bf16). Tile 64x64, 256 thr, 4 waves 2x2.
// XCD-swizzled block mapping: blocks on one XCD share G/B column panels.
__global__ __launch_bounds__(256, 4) void fused1_v2(
    const float* __restrict__ u, const float* __restrict__ w,
    const bf16_t* __restrict__ ubf, const bf16_t* __restrict__ wbf,
    const bf16_t* __restrict__ Gbf, const bf16_t* __restrict__ Bbf,
    const float* __restrict__ bias_p, const float* __restrict__ bias_q,
    bf16_t* __restrict__ pq) {
  __shared__ bf16_t lds[2][4][64 * 32];
  const int tid = threadIdx.x, lane = tid & 63, wv = tid >> 6;
  // bijective XCD swizzle (nwg=1024, 8 XCDs, cpx=128), col-major decomposition
  const int bid = blockIdx.x;
  const int t = (bid & 7) * 128 + (bid >> 3);
  const int row0 = (t & 15) * 64, col0 = (t >> 4) * 64;
  const int wm = (wv >> 1) * 32, wn = (wv & 1) * 32;
  const int lr = lane & 15, kq = lane >> 4;
  const int fslot = (kq ^ ((lr >> 1) & 3)) << 3;

  // staging: 1 cell (16B) per thread per tile; pre-swizzled global source
  const int sr = tid >> 2, skl = tid & 3;
  const int sks = skl ^ ((sr >> 1) & 3);
  const bf16_t* gsrc[4];
  gsrc[0] = ubf + (size_t)(row0 + sr) * NB + (sks << 3);
  gsrc[1] = wbf + (size_t)(row0 + sr) * NB + (sks << 3);
  gsrc[2] = Gbf + (size_t)(col0 + sr) * NB + (sks << 3);
  gsrc[3] = Bbf + (size_t)(col0 + sr) * NB + (sks << 3);
  const int ldsbase = wv * 512;  // wave-uniform dest (bf16 units)

  f32x4 aS[2][2] = {}, aT[2][2] = {};

#define STAGE1(buf, kt)                                                        \
  {                                                                            \
    _Pragma("unroll") for (int tt = 0; tt < 4; ++tt)                           \
        __builtin_amdgcn_global_load_lds(                                      \
            (const __attribute__((address_space(1))) unsigned int*)(gsrc[tt] + \
                                                                    (kt)),     \
            (__attribute__((address_space(3))) unsigned int*)(&lds[buf][tt]    \
                                                                  [ldsbase]),  \
            16, 0, 0);                                                         \
  }

  STAGE1(0, 0);
  __syncthreads();

  int cur = 0;
  for (int kt = 0; kt < NB; kt += 32) {
    if (kt + 32 < NB) STAGE1(cur ^ 1, kt + 32);
    bf16x8 au[2], aw[2], bG[2], bB[2];
#pragma unroll
    for (int m = 0; m < 2; ++m) {
      int off = (wm + m * 16 + lr) * 32 + fslot;
      au[m] = *reinterpret_cast<const bf16x8*>(&lds[cur][0][off]);
      aw[m] = *reinterpret_cast<const bf16x8*>(&lds[cur][1][off]);
    }
#pragma unroll
    for (int n = 0; n < 2; ++n) {
      int off = (wn + n * 16 + lr) * 32 + fslot;
      bG[n] = *reinterpret_cast<const bf16x8*>(&lds[cur][2][off]);
      bB[n] = *reinterpret_cast<const bf16x8*>(&lds[cur][3][off]);
    }
#pragma unroll
    for (int m = 0; m < 2; ++m)
#pragma unroll
      for (int n = 0; n < 2; ++n) {
        bf16x8 bn = neg8(bB[n]);
        aS[m][n] = __builtin_amdgcn_mfma_f32_16x16x32_bf16(au[m], bG[n], aS[m][n], 0, 0, 0);
        aS[m][n] = __builtin_amdgcn_mfma_f32_16x16x32_bf16(aw[m], bn, aS[m][n], 0, 0, 0);
        aT[m][n] = __builtin_amdgcn_mfma_f32_16x16x32_bf16(aw[m], bG[n], aT[m][n], 0, 0, 0);
        aT[m][n] = __builtin_amdgcn_mfma_f32_16x16x32_bf16(au[m], bB[n], aT[m][n], 0, 0, 0);
      }
    __syncthreads();
    cur ^= 1;
  }

  const int fr = lane & 15, fq = lane >> 4;
#pragma unroll
  for (int m = 0; m < 2; ++m)
#pragma unroll
    for (int n = 0; n < 2; ++n)
#pragma unroll
      for (int j = 0; j < 4; ++j) {
        int r = row0 + wm + m * 16 + fq * 4 + j;
        int c = col0 + wn + n * 16 + fr;
        size_t idx = (size_t)r * NB + c;
        float U = u[idx], W = w[idx];
        float S = aS[m][n][j], T = aT[m][n][j];
        pq[idx] = (bf16_t)(U * S + W * T + bias_p[c]);
        pq[SZ + idx] = (bf16_t)(W * S - U * T + bias_q[c]);
      }
}

// ---------------- stage 2: out_z = pq_z @ W_z^T + b_z ----------------
// Both operands bf16 via gload_lds; fused1-style 2-phase dbuf.
// Tile 128x128, 4 waves 2x2 (wave 64x64). Grid 1D = 512, XCD-swizzled.
__global__ __launch_bounds__(256, 2) void gemm2_v3(
    const bf16_t* __restrict__ pq, const bf16_t* __restrict__ Wpb,
    const bf16_t* __restrict__ Wqb, const float* __restrict__ bp,
    const float* __restrict__ bq, float* __restrict__ out) {
  __shared__ bf16_t lA[2][128 * 32], lW[2][128 * 32];
  const int tid = threadIdx.x, lane = tid & 63, wv = tid >> 6;
  // bijective XCD swizzle (nwg=512, cpx=64), z-major then col-major
  const int bid = blockIdx.x;
  const int t = (bid & 7) * 64 + (bid >> 3);
  const int z = t >> 8;
  const int s = t & 255;
  const int row0 = (s & 7) * 128, col0 = (s >> 3) * 128;

  const bf16_t* A = pq + (size_t)z * SZ;
  const bf16_t* Wm = z ? Wqb : Wpb;
  const float* bias = z ? bq : bp;
  float* C = out + (size_t)z * SZ;

  const int wm = (wv >> 1) * 64, wn = (wv & 1) * 64;
  const int lr = lane & 15, kq = lane >> 4;
  const int fslot = (kq ^ ((lr >> 1) & 3)) << 3;

  f32x4 acc[4][4] = {};

  // staging: 2 cells/thread for A, 2 for W (pre-swizzled global source)
  const bf16_t* gA[2];
  const bf16_t* gW[2];
  int cbase[2];
#pragma unroll
  for (int p = 0; p < 2; ++p) {
    int cb = p * 256 + wv * 64;
    cbase[p] = cb;
    int ci = cb + lane;
    int r = ci >> 2, kl = ci & 3;
    int ks = kl ^ ((r >> 1) & 3);
    gA[p] = A + (size_t)(row0 + r) * NB + (ks << 3);
    gW[p] = Wm + (size_t)(col0 + r) * NB + (ks << 3);
  }

#define STAGE2(buf, kt)                                                        \
  {                                                                            \
    _Pragma("unroll") for (int p = 0; p < 2; ++p) {                            \
      __builtin_amdgcn_global_load_lds(                                        \
          (const __attribute__((address_space(1))) unsigned int*)(gA[p] +      \
                                                                  (kt)),       \
          (__attribute__((address_space(3))) unsigned int*)(&lA[buf]           \
                                                               [cbase[p] * 8]),\
          16, 0, 0);                                                           \
      __builtin_amdgcn_global_load_lds(                                        \
          (const __attribute__((address_space(1))) unsigned int*)(gW[p] +      \
                                                                  (kt)),       \
          (__attribute__((address_space(3))) unsigned int*)(&lW[buf]           \
                                                               [cbase[p] * 8]),\
          16, 0, 0);                                                           \
    }                                                                          \
  }

  STAGE2(0, 0);
  __syncthreads();

  int cur = 0;
  for (int kt = 0; kt < NB; kt += 32) {
    if (kt + 32 < NB) STAGE2(cur ^ 1, kt + 32);
    bf16x8 af[4], bg[4];
#pragma unroll
    for (int m = 0; m < 4; ++m)
      af[m] = *reinterpret_cast<const bf16x8*>(&lA[cur][(wm + m * 16 + lr) * 32 + fslot]);
#pragma unroll
    for (int n = 0; n < 4; ++n)
      bg[n] = *reinterpret_cast<const bf16x8*>(&lW[cur][(wn + n * 16 + lr) * 32 + fslot]);
#pragma unroll
    for (int m = 0; m < 4; ++m)
#pragma unroll
      for (int n = 0; n < 4; ++n)
        acc[m][n] = __builtin_amdgcn_mfma_f32_16x16x32_bf16(af[m], bg[n], acc[m][n], 0, 0, 0);
    __syncthreads();
    cur ^= 1;
  }

  const int fr = lane & 15, fq = lane >> 4;
#pragma unroll
  for (int m = 0; m < 4; ++m)
#pragma unroll
    for (int n = 0; n < 4; ++n)
#pragma unroll
      for (int j = 0; j < 4; ++j) {
        int r = row0 + wm + m * 16 + fq * 4 + j;
        int c = col0 + wn + n * 16 + fr;
        C[(size_t)r * NB + c] = acc[m][n][j] + bias[c];
      }
}

// ---------------- middle fallback: gemm2 with f32 W (round-2 style) --------
__device__ __forceinline__ void fb_stage_f32(const float* __restrict__ src,
                                             int row0, int k0, bf16_t* lds, int t) {
  int r = t >> 2, kk = t & 3;
  const float* p = src + (size_t)(row0 + r) * NB + k0 + (kk << 3);
  float4 v0 = *reinterpret_cast<const float4*>(p);
  float4 v1 = *reinterpret_cast<const float4*>(p + 4);
  *reinterpret_cast<bf16x8*>(lds + swz_off(r, kk)) = cvt8(v0, v1);
}

__global__ __launch_bounds__(256, 2) void fb_gemm2(
    const bf16_t* __restrict__ pq, const float* __restrict__ Wp,
    const float* __restrict__ Wq, const float* __restrict__ bp,
    const float* __restrict__ bq, float* __restrict__ out) {
  __shared__ bf16_t lA[128 * 32], lW[128 * 32];
  const int z = blockIdx.z;
  const bf16_t* A = pq + (size_t)z * SZ;
  const float* Wm = z ? Wq : Wp;
  const float* bias = z ? bq : bp;
  float* C = out + (size_t)z * SZ;
  const int tid = threadIdx.x;
  const int lane = tid & 63, wv = tid >> 6;
  const int wm = (wv >> 1) * 64, wn = (wv & 1) * 64;
  const int row0 = blockIdx.y * 128, col0 = blockIdx.x * 128;
  const int lr = lane & 15, kq = lane >> 4;
  const int fslot = (kq ^ ((lr >> 1) & 3)) << 3;
  f32x4 acc[4][4] = {};
  for (int kt = 0; kt < NB; kt += 32) {
#pragma unroll
    for (int p = 0; p < 2; ++p) {
      int cb = p * 256 + wv * 64;
      int ci = cb + lane;
      int r = ci >> 2, kl = ci & 3;
      int ks = kl ^ ((r >> 1) & 3);
      const bf16_t* g = A + (size_t)(row0 + r) * NB + kt + (ks << 3);
      __builtin_amdgcn_global_load_lds(
          (const __attribute__((address_space(1))) unsigned int*)g,
          (__attribute__((address_space(3))) unsigned int*)(lA + cb * 8),
          16, 0, 0);
    }
#pragma unroll
    for (int p = 0; p < 2; ++p)
      fb_stage_f32(Wm, col0, kt, lW, p * 256 + tid);
    __syncthreads();
    bf16x8 af[4], bg[4];
#pragma unroll
    for (int m = 0; m < 4; ++m)
      af[m] = *reinterpret_cast<const bf16x8*>(lA + (wm + m * 16 + lr) * 32 + fslot);
#pragma unroll
    for (int n = 0; n < 4; ++n)
      bg[n] = *reinterpret_cast<const bf16x8*>(lW + (wn + n * 16 + lr) * 32 + fslot);
#pragma unroll
    for (int m = 0; m < 4; ++m)
#pragma unroll
      for (int n = 0; n < 4; ++n)
        acc[m][n] = __builtin_amdgcn_mfma_f32_16x16x32_bf16(af[m], bg[n], acc[m][n], 0, 0, 0);
    __syncthreads();
  }
  const int fr = lane & 15, fq = lane >> 4;
#pragma unroll
  for (int m = 0; m < 4; ++m)
#pragma unroll
    for (int n = 0; n < 4; ++n)
#pragma unroll
      for (int j = 0; j < 4; ++j) {
        int r = row0 + wm + m * 16 + fq * 4 + j;
        int c = col0 + wn + n * 16 + fr;
        C[(size_t)r * NB + c] = acc[m][n][j] + bias[c];
      }
}

// ---------------- last-resort fallback (no ws prep) ----------------
__global__ __launch_bounds__(512, 2) void fb_fused1(
    const float* __restrict__ u, const float* __restrict__ w,
    const float* __restrict__ G, const float* __restrict__ Bm,
    const float* __restrict__ bias_p, const float* __restrict__ bias_q,
    bf16_t* __restrict__ pq) {
  __shared__ bf16_t lU[128 * 32], lW[128 * 32], lG[128 * 32], lB[128 * 32];
  const int tid = threadIdx.x;
  const int lane = tid & 63, wv = tid >> 6;
  const int wm = (wv >> 2) * 64, wn = (wv & 3) * 32;
  const int row0 = blockIdx.y * 128, col0 = blockIdx.x * 128;
  const int lr = lane & 15, kq = lane >> 4;
  const int fslot = (kq ^ ((lr >> 1) & 3)) << 3;
  f32x4 aS[4][2] = {}, aT[4][2] = {};
  for (int kt = 0; kt < NB; kt += 32) {
    fb_stage_f32(u, row0, kt, lU, tid);
    fb_stage_f32(w, row0, kt, lW, tid);
    fb_stage_f32(G, col0, kt, lG, tid);
    fb_stage_f32(Bm, col0, kt, lB, tid);
    __syncthreads();
    bf16x8 au[4], aw[4], bG[2], bB[2], bBn[2];
#pragma unroll
    for (int m = 0; m < 4; ++m) {
      int off = (wm + m * 16 + lr) * 32 + fslot;
      au[m] = *reinterpret_cast<const bf16x8*>(lU + off);
      aw[m] = *reinterpret_cast<const bf16x8*>(lW + off);
    }
#pragma unroll
    for (int n = 0; n < 2; ++n) {
      int off = (wn + n * 16 + lr) * 32 + fslot;
      bG[n] = *reinterpret_cast<const bf16x8*>(lG + off);
      bB[n] = *reinterpret_cast<const bf16x8*>(lB + off);
      bBn[n] = neg8(bB[n]);
    }
#pragma unroll
    for (int m = 0; m < 4; ++m)
#pragma unroll
      for (int n = 0; n < 2; ++n) {
        aS[m][n] = __builtin_amdgcn_mfma_f32_16x16x32_bf16(au[m], bG[n], aS[m][n], 0, 0, 0);
        aS[m][n] = __builtin_amdgcn_mfma_f32_16x16x32_bf16(aw[m], bBn[n], aS[m][n], 0, 0, 0);
        aT[m][n] = __builtin_amdgcn_mfma_f32_16x16x32_bf16(aw[m], bG[n], aT[m][n], 0, 0, 0);
        aT[m][n] = __builtin_amdgcn_mfma_f32_16x16x32_bf16(au[m], bB[n], aT[m][n], 0, 0, 0);
      }
    __syncthreads();
  }
  const int fr = lane & 15, fq = lane >> 4;
#pragma unroll
  for (int m = 0; m < 4; ++m)
#pragma unroll
    for (int n = 0; n < 2; ++n)
#pragma unroll
      for (int j = 0; j < 4; ++j) {
        int r = row0 + wm + m * 16 + fq * 4 + j;
        int c = col0 + wn + n * 16 + fr;
        size_t idx = (size_t)r * NB + c;
        float U = u[idx], W = w[idx];
        float S = aS[m][n][j], T = aT[m][n][j];
        pq[idx] = (bf16_t)(U * S + W * T + bias_p[c]);
        pq[SZ + idx] = (bf16_t)(W * S - U * T + bias_q[c]);
      }
}

extern "C" void kernel_launch(void* const* d_in, const int* in_sizes, int n_in,
                              void* d_out, int out_size, void* d_ws, size_t ws_size,
                              hipStream_t stream) {
  const float* u = (const float*)d_in[0];
  const float* w = (const float*)d_in[1];
  const float* G = (const float*)d_in[2];
  const float* Bm = (const float*)d_in[3];
  const float* bias_p = (const float*)d_in[4];
  const float* bias_q = (const float*)d_in[5];
  const float* Wp = (const float*)d_in[6];
  const float* bp = (const float*)d_in[7];
  const float* Wq = (const float*)d_in[8];
  const float* bq = (const float*)d_in[9];
  (void)in_sizes; (void)n_in; (void)out_size;

  const size_t need_full = (4 * SZ + 4 * NN) * sizeof(bf16_t);  // ~168 MB
  const size_t need_mid = (4 * SZ + 2 * NN) * sizeof(bf16_t);   // ~101 MB

  if (ws_size >= need_full) {
    bf16_t* ws = (bf16_t*)d_ws;
    bf16_t* ubf = ws;
    bf16_t* wbf = ws + SZ;
    bf16_t* Gbf = ws + 2 * SZ;
    bf16_t* Bbf = Gbf + NN;
    bf16_t* Wpb = Bbf + NN;
    bf16_t* Wqb = Wpb + NN;
    bf16_t* pqw = Wqb + NN;
    prep6_kernel<<<2048, 256, 0, stream>>>(u, w, G, Bm, Wp, Wq, ws);
    fused1_v2<<<1024, 256, 0, stream>>>(u, w, ubf, wbf, Gbf, Bbf,
                                        bias_p, bias_q, pqw);
    gemm2_v3<<<512, 256, 0, stream>>>(pqw, Wpb, Wqb, bp, bq, (float*)d_out);
  } else if (ws_size >= need_mid) {
    bf16_t* ws = (bf16_t*)d_ws;
    bf16_t* ubf = ws;
    bf16_t* wbf = ws + SZ;
    bf16_t* Gbf = ws + 2 * SZ;
    bf16_t* Bbf = Gbf + NN;
    bf16_t* pqw = Bbf + NN;
    prep4_kernel<<<2048, 256, 0, stream>>>(u, w, G, Bm, ws);
    fused1_v2<<<1024, 256, 0, stream>>>(u, w, ubf, wbf, Gbf, Bbf,
                                        bias_p, bias_q, pqw);
    fb_gemm2<<<dim3(NB / 128, MB / 128, 2), 256, 0, stream>>>(
        pqw, Wp, Wq, bp, bq, (float*)d_out);
  } else {
    bf16_t* pqw = (bf16_t*)d_ws;
    fb_fused1<<<dim3(NB / 128, MB / 128), 512, 0, stream>>>(
        u, w, G, Bm, bias_p, bias_q, pqw);
    fb_gemm2<<<dim3(NB / 128, MB / 128, 2), 256, 0, stream>>>(
        pqw, Wp, Wq, bp, bq, (float*)d_out);
  }
}

// Round 5
// 340.758 us; speedup vs baseline: 1.4355x; 1.0855x over previous
//
#include <hip/hip_runtime.h>
#include <hip/hip_bf16.h>

#define NB 4096
#define MB 1024
#define SZ ((size_t)MB * NB)
#define NN ((size_t)NB * NB)

typedef __bf16 bf16_t;
typedef __attribute__((ext_vector_type(8))) __bf16 bf16x8;
typedef __attribute__((ext_vector_type(4))) float f32x4;
typedef __attribute__((ext_vector_type(4))) unsigned int u32x4;

#define AS1 __attribute__((address_space(1)))
#define AS3 __attribute__((address_space(3)))

// LDS tile: rows x 64 k (bf16), cells of 8 bf16 (16B), 8 cells/row.
// cell (r, kk) stored at slot s = kk ^ (r&7): 16 lanes reading same kk across
// rows hit 8 distinct slots (2-way = free). gload_lds writes linearly; the
// global SOURCE is pre-swizzled (fetch chunk kk = s ^ (r&7)).

__device__ __forceinline__ bf16x8 neg8(bf16x8 x) {
  u32x4 t;
  __builtin_memcpy(&t, &x, 16);
  t ^= 0x80008000u;
  bf16x8 y;
  __builtin_memcpy(&y, &t, 16);
  return y;
}

__device__ __forceinline__ bf16x8 cvt8(float4 a, float4 b) {
  bf16x8 v;
  v[0] = (bf16_t)a.x; v[1] = (bf16_t)a.y; v[2] = (bf16_t)a.z; v[3] = (bf16_t)a.w;
  v[4] = (bf16_t)b.x; v[5] = (bf16_t)b.y; v[6] = (bf16_t)b.z; v[7] = (bf16_t)b.w;
  return v;
}

#define MFMA16(a, b, c) __builtin_amdgcn_mfma_f32_16x16x32_bf16((a), (b), (c), 0, 0, 0)

// ---------------- prep: f32 -> bf16 ----------------
#define ITEM_S (SZ / 8)
#define ITEM_N (NN / 8)

__global__ __launch_bounds__(256) void prep6_kernel(
    const float* __restrict__ u, const float* __restrict__ w,
    const float* __restrict__ G, const float* __restrict__ Bm,
    const float* __restrict__ Wp, const float* __restrict__ Wq,
    bf16_t* __restrict__ ws) {
  size_t stride = (size_t)gridDim.x * blockDim.x;
  const size_t tot = 2 * ITEM_S + 4 * ITEM_N;
  for (size_t i = (size_t)blockIdx.x * blockDim.x + threadIdx.x; i < tot;
       i += stride) {
    const float* src;
    bf16_t* dst;
    size_t off;
    if (i < ITEM_S) { src = u; dst = ws; off = i; }
    else if (i < 2 * ITEM_S) { src = w; dst = ws + SZ; off = i - ITEM_S; }
    else if (i < 2 * ITEM_S + ITEM_N) { src = G; dst = ws + 2 * SZ; off = i - 2 * ITEM_S; }
    else if (i < 2 * ITEM_S + 2 * ITEM_N) { src = Bm; dst = ws + 2 * SZ + NN; off = i - 2 * ITEM_S - ITEM_N; }
    else if (i < 2 * ITEM_S + 3 * ITEM_N) { src = Wp; dst = ws + 2 * SZ + 2 * NN; off = i - 2 * ITEM_S - 2 * ITEM_N; }
    else { src = Wq; dst = ws + 2 * SZ + 3 * NN; off = i - 2 * ITEM_S - 3 * ITEM_N; }
    const float4* s = reinterpret_cast<const float4*>(src) + off * 2;
    reinterpret_cast<bf16x8*>(dst)[off] = cvt8(s[0], s[1]);
  }
}

__global__ __launch_bounds__(256) void prep4_kernel(
    const float* __restrict__ u, const float* __restrict__ w,
    const float* __restrict__ G, const float* __restrict__ Bm,
    bf16_t* __restrict__ ws) {
  size_t stride = (size_t)gridDim.x * blockDim.x;
  const size_t tot = 2 * ITEM_S + 2 * ITEM_N;
  for (size_t i = (size_t)blockIdx.x * blockDim.x + threadIdx.x; i < tot;
       i += stride) {
    const float* src;
    bf16_t* dst;
    size_t off;
    if (i < ITEM_S) { src = u; dst = ws; off = i; }
    else if (i < 2 * ITEM_S) { src = w; dst = ws + SZ; off = i - ITEM_S; }
    else if (i < 2 * ITEM_S + ITEM_N) { src = G; dst = ws + 2 * SZ; off = i - 2 * ITEM_S; }
    else { src = Bm; dst = ws + 2 * SZ + NN; off = i - 2 * ITEM_S - ITEM_N; }
    const float4* s = reinterpret_cast<const float4*>(src) + off * 2;
    reinterpret_cast<bf16x8*>(dst)[off] = cvt8(s[0], s[1]);
  }
}

// ---------------- fused stage 1, 8-phase schedule ----------------
// S = u@G^T - w@B^T, T = w@G^T + u@B^T; p_mid = u*S + w*T + bias_p,
// q_mid = w*S - u*T + bias_q (bf16 out).
// Tile 128x128, BK=64, 512 thr / 8 waves (2m x 4n, wave 64x32), LDS 128KB.
// Per K-tile: 4 phases {ds_read frags | prefetch issue | barrier | 16 MFMA |
// barrier}; vmcnt(0) once per K-tile (prefetch issued phases 0-1).
__global__ __launch_bounds__(512, 2) void fused1_v3(
    const float* __restrict__ u, const float* __restrict__ w,
    const bf16_t* __restrict__ ubf, const bf16_t* __restrict__ wbf,
    const bf16_t* __restrict__ Gbf, const bf16_t* __restrict__ Bbf,
    const float* __restrict__ bias_p, const float* __restrict__ bias_q,
    bf16_t* __restrict__ pq) {
  __shared__ bf16_t lds[2][4][128 * 64];  // 128 KB
  const int tid = threadIdx.x, lane = tid & 63, wv = tid >> 6;
  // grid 256 = 8 row-panels x 32 col-panels, XCD-swizzled (bijective)
  const int bid = blockIdx.x;
  const int t = (bid & 7) * 32 + (bid >> 3);
  const int row0 = (t & 7) * 128, col0 = (t >> 3) * 128;
  const int wm = (wv >> 2) * 64, wn = (wv & 3) * 32;
  const int lr = lane & 15, kq = lane >> 4;

  // staging: thread stages 2 cells per op (rows rA and rA+64, same chunk)
  const int rA = tid >> 3;
  const int kkc = (tid & 7) ^ (rA & 7);
  const bf16_t* bases[4] = {ubf, wbf, Gbf, Bbf};
  const int r0s[4] = {row0, row0, col0, col0};
  const bf16_t* gsA[4];
  const bf16_t* gsB[4];
#pragma unroll
  for (int o = 0; o < 4; ++o) {
    gsA[o] = bases[o] + (size_t)(r0s[o] + rA) * NB + kkc * 8;
    gsB[o] = gsA[o] + (size_t)64 * NB;
  }

#define F1_ST(bufv, o, ktn)                                                    \
  do {                                                                         \
    __builtin_amdgcn_global_load_lds(                                          \
        (const AS1 unsigned int*)(gsA[o] + (ktn)),                             \
        (AS3 unsigned int*)(&lds[bufv][o][wv * 512]), 16, 0, 0);               \
    __builtin_amdgcn_global_load_lds(                                          \
        (const AS1 unsigned int*)(gsB[o] + (ktn)),                             \
        (AS3 unsigned int*)(&lds[bufv][o][4096 + wv * 512]), 16, 0, 0);        \
  } while (0)

  // frag read offsets (bf16 units)
  int kread[2], aoff[4], boff[2];
#pragma unroll
  for (int ks = 0; ks < 2; ++ks) kread[ks] = ((ks * 4 + kq) ^ (lr & 7)) << 3;
#pragma unroll
  for (int m = 0; m < 4; ++m) aoff[m] = (wm + m * 16 + lr) * 64;
#pragma unroll
  for (int n = 0; n < 2; ++n) boff[n] = (wn + n * 16 + lr) * 64;

#define F1_LD(o, roff, ks) \
  (*reinterpret_cast<const bf16x8*>(&lds[cur][o][(roff) + kread[ks]]))

  f32x4 aS[4][2] = {}, aT[4][2] = {};

  // prologue: stage K-tile 0
  {
    F1_ST(0, 0, 0); F1_ST(0, 1, 0); F1_ST(0, 2, 0); F1_ST(0, 3, 0);
    asm volatile("s_waitcnt vmcnt(0)" ::: "memory");
  }
  __syncthreads();

  const int NIT = NB / 64;
  for (int it = 0; it < NIT; ++it) {
    const int cur = it & 1;
    const int nxt = cur ^ 1;
    const bool pf = (it + 1) < NIT;
    const int ktn = (it + 1) * 64;
#pragma unroll
    for (int ks = 0; ks < 2; ++ks) {
      bf16x8 bG[2], bB[2], bBn[2];
#pragma unroll
      for (int mh = 0; mh < 2; ++mh) {
        if (mh == 0) {
          bG[0] = F1_LD(2, boff[0], ks);
          bG[1] = F1_LD(2, boff[1], ks);
          bB[0] = F1_LD(3, boff[0], ks);
          bB[1] = F1_LD(3, boff[1], ks);
          bBn[0] = neg8(bB[0]);
          bBn[1] = neg8(bB[1]);
        }
        bf16x8 au2[2], aw2[2];
#pragma unroll
        for (int i = 0; i < 2; ++i) {
          au2[i] = F1_LD(0, aoff[2 * mh + i], ks);
          aw2[i] = F1_LD(1, aoff[2 * mh + i], ks);
        }
        // prefetch issue in phases 0 and 1 (ks==0)
        if (ks == 0 && pf) {
          if (mh == 0) { F1_ST(nxt, 0, ktn); F1_ST(nxt, 1, ktn); }
          else         { F1_ST(nxt, 2, ktn); F1_ST(nxt, 3, ktn); }
        }
        __builtin_amdgcn_s_barrier();
        __builtin_amdgcn_sched_barrier(0);
        __builtin_amdgcn_s_setprio(1);
#pragma unroll
        for (int i = 0; i < 2; ++i) {
          const int m = 2 * mh + i;
#pragma unroll
          for (int n = 0; n < 2; ++n) {
            aS[m][n] = MFMA16(au2[i], bG[n], aS[m][n]);
            aS[m][n] = MFMA16(aw2[i], bBn[n], aS[m][n]);
            aT[m][n] = MFMA16(aw2[i], bG[n], aT[m][n]);
            aT[m][n] = MFMA16(au2[i], bB[n], aT[m][n]);
          }
        }
        __builtin_amdgcn_s_setprio(0);
        __builtin_amdgcn_sched_barrier(0);
        if (ks == 1 && mh == 1)
          asm volatile("s_waitcnt vmcnt(0)" ::: "memory");
        __builtin_amdgcn_s_barrier();
        __builtin_amdgcn_sched_barrier(0);
      }
    }
  }

  // epilogue: combine with u,w f32 + biases, write p_mid/q_mid bf16
  const int fr = lane & 15, fq = kq;
#pragma unroll
  for (int m = 0; m < 4; ++m)
#pragma unroll
    for (int n = 0; n < 2; ++n)
#pragma unroll
      for (int j = 0; j < 4; ++j) {
        int r = row0 + wm + m * 16 + fq * 4 + j;
        int c = col0 + wn + n * 16 + fr;
        size_t idx = (size_t)r * NB + c;
        float U = u[idx], W = w[idx];
        float S = aS[m][n][j], T = aT[m][n][j];
        pq[idx] = (bf16_t)(U * S + W * T + bias_p[c]);
        pq[SZ + idx] = (bf16_t)(W * S - U * T + bias_q[c]);
      }
}

// ---------------- stage 2, 8-phase schedule ----------------
// out_z = pq_z @ W_z^T + b_z (f32). Tile 128(M)x256(N), BK=64, 512 thr /
// 8 waves (2m x 4n, wave 64x64), LDS 96KB. Grid 256 (8x16x2), XCD-swizzled.
__global__ __launch_bounds__(512, 2) void gemm2_v4(
    const bf16_t* __restrict__ pq, const bf16_t* __restrict__ Wpb,
    const bf16_t* __restrict__ Wqb, const float* __restrict__ bp,
    const float* __restrict__ bq, float* __restrict__ out) {
  __shared__ bf16_t lA[2][128 * 64];  // 32 KB
  __shared__ bf16_t lW[2][256 * 64];  // 64 KB
  const int tid = threadIdx.x, lane = tid & 63, wv = tid >> 6;
  const int bid = blockIdx.x;
  const int t = (bid & 7) * 32 + (bid >> 3);
  const int z = t >> 7;
  const int s = t & 127;
  const int row0 = (s & 7) * 128, col0 = (s >> 3) * 256;

  const bf16_t* A = pq + (size_t)z * SZ;
  const bf16_t* Wm = z ? Wqb : Wpb;
  const float* bias = z ? bq : bp;
  float* C = out + (size_t)z * SZ;

  const int wm = (wv >> 2) * 64, wn = (wv & 3) * 64;
  const int lr = lane & 15, kq = lane >> 4;

  const int rA = tid >> 3;
  const int kkc = (tid & 7) ^ (rA & 7);
  const bf16_t* gA_[2];
  const bf16_t* gW_[4];
#pragma unroll
  for (int j = 0; j < 2; ++j)
    gA_[j] = A + (size_t)(row0 + rA + 64 * j) * NB + kkc * 8;
#pragma unroll
  for (int j = 0; j < 4; ++j)
    gW_[j] = Wm + (size_t)(col0 + rA + 64 * j) * NB + kkc * 8;

#define G2_STA(bufv, j, ktn)                                                   \
  __builtin_amdgcn_global_load_lds(                                            \
      (const AS1 unsigned int*)(gA_[j] + (ktn)),                               \
      (AS3 unsigned int*)(&lA[bufv][(j) * 4096 + wv * 512]), 16, 0, 0)
#define G2_STW(bufv, j, ktn)                                                   \
  __builtin_amdgcn_global_load_lds(                                            \
      (const AS1 unsigned int*)(gW_[j] + (ktn)),                               \
      (AS3 unsigned int*)(&lW[bufv][(j) * 4096 + wv * 512]), 16, 0, 0)

  int kread[2], aoff[4], boff[4];
#pragma unroll
  for (int ks = 0; ks < 2; ++ks) kread[ks] = ((ks * 4 + kq) ^ (lr & 7)) << 3;
#pragma unroll
  for (int m = 0; m < 4; ++m) aoff[m] = (wm + m * 16 + lr) * 64;
#pragma unroll
  for (int n = 0; n < 4; ++n) boff[n] = (wn + n * 16 + lr) * 64;

  f32x4 acc[4][4] = {};

  {
    G2_STA(0, 0, 0); G2_STA(0, 1, 0);
    G2_STW(0, 0, 0); G2_STW(0, 1, 0); G2_STW(0, 2, 0); G2_STW(0, 3, 0);
    asm volatile("s_waitcnt vmcnt(0)" ::: "memory");
  }
  __syncthreads();

  const int NIT = NB / 64;
  for (int it = 0; it < NIT; ++it) {
    const int cur = it & 1;
    const int nxt = cur ^ 1;
    const bool pf = (it + 1) < NIT;
    const int ktn = (it + 1) * 64;
#pragma unroll
    for (int ks = 0; ks < 2; ++ks) {
      bf16x8 bw[4];
#pragma unroll
      for (int mh = 0; mh < 2; ++mh) {
        if (mh == 0) {
#pragma unroll
          for (int n = 0; n < 4; ++n)
            bw[n] = *reinterpret_cast<const bf16x8*>(
                &lW[cur][boff[n] + kread[ks]]);
        }
        bf16x8 au2[2];
#pragma unroll
        for (int i = 0; i < 2; ++i)
          au2[i] = *reinterpret_cast<const bf16x8*>(
              &lA[cur][aoff[2 * mh + i] + kread[ks]]);
        if (pf) {
          const int ph = ks * 2 + mh;
          if (ph == 0) { G2_STA(nxt, 0, ktn); G2_STA(nxt, 1, ktn); }
          else if (ph == 1) { G2_STW(nxt, 0, ktn); G2_STW(nxt, 1, ktn); }
          else if (ph == 2) { G2_STW(nxt, 2, ktn); G2_STW(nxt, 3, ktn); }
        }
        __builtin_amdgcn_s_barrier();
        __builtin_amdgcn_sched_barrier(0);
        __builtin_amdgcn_s_setprio(1);
#pragma unroll
        for (int i = 0; i < 2; ++i) {
          const int m = 2 * mh + i;
#pragma unroll
          for (int n = 0; n < 4; ++n)
            acc[m][n] = MFMA16(au2[i], bw[n], acc[m][n]);
        }
        __builtin_amdgcn_s_setprio(0);
        __builtin_amdgcn_sched_barrier(0);
        if (ks == 1 && mh == 1)
          asm volatile("s_waitcnt vmcnt(0)" ::: "memory");
        __builtin_amdgcn_s_barrier();
        __builtin_amdgcn_sched_barrier(0);
      }
    }
  }

  const int fr = lane & 15, fq = kq;
#pragma unroll
  for (int m = 0; m < 4; ++m)
#pragma unroll
    for (int n = 0; n < 4; ++n)
#pragma unroll
      for (int j = 0; j < 4; ++j) {
        int r = row0 + wm + m * 16 + fq * 4 + j;
        int c = col0 + wn + n * 16 + fr;
        C[(size_t)r * NB + c] = acc[m][n][j] + bias[c];
      }
}

// ---------------- fallbacks ----------------
__device__ __forceinline__ int swz_off32(int r, int kk) {
  return r * 32 + ((kk ^ ((r >> 1) & 3)) << 3);
}

__device__ __forceinline__ void fb_stage_f32(const float* __restrict__ src,
                                             int row0, int k0, bf16_t* lds, int t) {
  int r = t >> 2, kk = t & 3;
  const float* p = src + (size_t)(row0 + r) * NB + k0 + (kk << 3);
  float4 v0 = *reinterpret_cast<const float4*>(p);
  float4 v1 = *reinterpret_cast<const float4*>(p + 4);
  *reinterpret_cast<bf16x8*>(lds + swz_off32(r, kk)) = cvt8(v0, v1);
}

__global__ __launch_bounds__(256, 2) void fb_gemm2(
    const bf16_t* __restrict__ pq, const float* __restrict__ Wp,
    const float* __restrict__ Wq, const float* __restrict__ bp,
    const float* __restrict__ bq, float* __restrict__ out) {
  __shared__ bf16_t lA[128 * 32], lW[128 * 32];
  const int z = blockIdx.z;
  const bf16_t* A = pq + (size_t)z * SZ;
  const float* Wm = z ? Wq : Wp;
  const float* bias = z ? bq : bp;
  float* C = out + (size_t)z * SZ;
  const int tid = threadIdx.x;
  const int lane = tid & 63, wv = tid >> 6;
  const int wm = (wv >> 1) * 64, wn = (wv & 1) * 64;
  const int row0 = blockIdx.y * 128, col0 = blockIdx.x * 128;
  const int lr = lane & 15, kq = lane >> 4;
  const int fslot = (kq ^ ((lr >> 1) & 3)) << 3;
  f32x4 acc[4][4] = {};
  for (int kt = 0; kt < NB; kt += 32) {
#pragma unroll
    for (int p = 0; p < 2; ++p) {
      int cb = p * 256 + wv * 64;
      int ci = cb + lane;
      int r = ci >> 2, kl = ci & 3;
      int ks = kl ^ ((r >> 1) & 3);
      const bf16_t* g = A + (size_t)(row0 + r) * NB + kt + (ks << 3);
      __builtin_amdgcn_global_load_lds((const AS1 unsigned int*)g,
                                       (AS3 unsigned int*)(lA + cb * 8), 16, 0, 0);
    }
#pragma unroll
    for (int p = 0; p < 2; ++p)
      fb_stage_f32(Wm, col0, kt, lW, p * 256 + tid);
    __syncthreads();
    bf16x8 af[4], bg[4];
#pragma unroll
    for (int m = 0; m < 4; ++m)
      af[m] = *reinterpret_cast<const bf16x8*>(lA + (wm + m * 16 + lr) * 32 + fslot);
#pragma unroll
    for (int n = 0; n < 4; ++n)
      bg[n] = *reinterpret_cast<const bf16x8*>(lW + (wn + n * 16 + lr) * 32 + fslot);
#pragma unroll
    for (int m = 0; m < 4; ++m)
#pragma unroll
      for (int n = 0; n < 4; ++n)
        acc[m][n] = MFMA16(af[m], bg[n], acc[m][n]);
    __syncthreads();
  }
  const int fr = lane & 15, fq = lane >> 4;
#pragma unroll
  for (int m = 0; m < 4; ++m)
#pragma unroll
    for (int n = 0; n < 4; ++n)
#pragma unroll
      for (int j = 0; j < 4; ++j) {
        int r = row0 + wm + m * 16 + fq * 4 + j;
        int c = col0 + wn + n * 16 + fr;
        C[(size_t)r * NB + c] = acc[m][n][j] + bias[c];
      }
}

__global__ __launch_bounds__(512, 2) void fb_fused1(
    const float* __restrict__ u, const float* __restrict__ w,
    const float* __restrict__ G, const float* __restrict__ Bm,
    const float* __restrict__ bias_p, const float* __restrict__ bias_q,
    bf16_t* __restrict__ pq) {
  __shared__ bf16_t lU[128 * 32], lW[128 * 32], lG[128 * 32], lB[128 * 32];
  const int tid = threadIdx.x;
  const int lane = tid & 63, wv = tid >> 6;
  const int wm = (wv >> 2) * 64, wn = (wv & 3) * 32;
  const int row0 = blockIdx.y * 128, col0 = blockIdx.x * 128;
  const int lr = lane & 15, kq = lane >> 4;
  const int fslot = (kq ^ ((lr >> 1) & 3)) << 3;
  f32x4 aS[4][2] = {}, aT[4][2] = {};
  for (int kt = 0; kt < NB; kt += 32) {
    fb_stage_f32(u, row0, kt, lU, tid);
    fb_stage_f32(w, row0, kt, lW, tid);
    fb_stage_f32(G, col0, kt, lG, tid);
    fb_stage_f32(Bm, col0, kt, lB, tid);
    __syncthreads();
    bf16x8 au[4], aw[4], bG[2], bB[2], bBn[2];
#pragma unroll
    for (int m = 0; m < 4; ++m) {
      int off = (wm + m * 16 + lr) * 32 + fslot;
      au[m] = *reinterpret_cast<const bf16x8*>(lU + off);
      aw[m] = *reinterpret_cast<const bf16x8*>(lW + off);
    }
#pragma unroll
    for (int n = 0; n < 2; ++n) {
      int off = (wn + n * 16 + lr) * 32 + fslot;
      bG[n] = *reinterpret_cast<const bf16x8*>(lG + off);
      bB[n] = *reinterpret_cast<const bf16x8*>(lB + off);
      bBn[n] = neg8(bB[n]);
    }
#pragma unroll
    for (int m = 0; m < 4; ++m)
#pragma unroll
      for (int n = 0; n < 2; ++n) {
        aS[m][n] = MFMA16(au[m], bG[n], aS[m][n]);
        aS[m][n] = MFMA16(aw[m], bBn[n], aS[m][n]);
        aT[m][n] = MFMA16(aw[m], bG[n], aT[m][n]);
        aT[m][n] = MFMA16(au[m], bB[n], aT[m][n]);
      }
    __syncthreads();
  }
  const int fr = lane & 15, fq = lane >> 4;
#pragma unroll
  for (int m = 0; m < 4; ++m)
#pragma unroll
    for (int n = 0; n < 2; ++n)
#pragma unroll
      for (int j = 0; j < 4; ++j) {
        int r = row0 + wm + m * 16 + fq * 4 + j;
        int c = col0 + wn + n * 16 + fr;
        size_t idx = (size_t)r * NB + c;
        float U = u[idx], W = w[idx];
        float S = aS[m][n][j], T = aT[m][n][j];
        pq[idx] = (bf16_t)(U * S + W * T + bias_p[c]);
        pq[SZ + idx] = (bf16_t)(W * S - U * T + bias_q[c]);
      }
}

extern "C" void kernel_launch(void* const* d_in, const int* in_sizes, int n_in,
                              void* d_out, int out_size, void* d_ws, size_t ws_size,
                              hipStream_t stream) {
  const float* u = (const float*)d_in[0];
  const float* w = (const float*)d_in[1];
  const float* G = (const float*)d_in[2];
  const float* Bm = (const float*)d_in[3];
  const float* bias_p = (const float*)d_in[4];
  const float* bias_q = (const float*)d_in[5];
  const float* Wp = (const float*)d_in[6];
  const float* bp = (const float*)d_in[7];
  const float* Wq = (const float*)d_in[8];
  const float* bq = (const float*)d_in[9];
  (void)in_sizes; (void)n_in; (void)out_size;

  const size_t need_full = (6 * SZ + 4 * NN) * sizeof(bf16_t);  // 176 MB
  const size_t need_mid = (6 * SZ + 2 * NN) * sizeof(bf16_t);   // 112 MB

  if (ws_size >= need_full) {
    bf16_t* ws = (bf16_t*)d_ws;
    bf16_t* ubf = ws;
    bf16_t* wbf = ws + SZ;
    bf16_t* Gbf = ws + 2 * SZ;
    bf16_t* Bbf = Gbf + NN;
    bf16_t* Wpb = Bbf + NN;
    bf16_t* Wqb = Wpb + NN;
    bf16_t* pqw = Wqb + NN;
    prep6_kernel<<<2048, 256, 0, stream>>>(u, w, G, Bm, Wp, Wq, ws);
    fused1_v3<<<256, 512, 0, stream>>>(u, w, ubf, wbf, Gbf, Bbf,
                                       bias_p, bias_q, pqw);
    gemm2_v4<<<256, 512, 0, stream>>>(pqw, Wpb, Wqb, bp, bq, (float*)d_out);
  } else if (ws_size >= need_mid) {
    bf16_t* ws = (bf16_t*)d_ws;
    bf16_t* ubf = ws;
    bf16_t* wbf = ws + SZ;
    bf16_t* Gbf = ws + 2 * SZ;
    bf16_t* Bbf = Gbf + NN;
    bf16_t* pqw = Bbf + NN;
    prep4_kernel<<<2048, 256, 0, stream>>>(u, w, G, Bm, ws);
    fused1_v3<<<256, 512, 0, stream>>>(u, w, ubf, wbf, Gbf, Bbf,
                                       bias_p, bias_q, pqw);
    fb_gemm2<<<dim3(NB / 128, MB / 128, 2), 256, 0, stream>>>(
        pqw, Wp, Wq, bp, bq, (float*)d_out);
  } else {
    bf16_t* pqw = (bf16_t*)d_ws;
    fb_fused1<<<dim3(NB / 128, MB / 128), 512, 0, stream>>>(
        u, w, G, Bm, bias_p, bias_q, pqw);
    fb_gemm2<<<dim3(NB / 128, MB / 128, 2), 256, 0, stream>>>(
        pqw, Wp, Wq, bp, bq, (float*)d_out);
  }
}

// Round 6
// 320.716 us; speedup vs baseline: 1.5252x; 1.0625x over previous
//
#include <hip/hip_runtime.h>
#include <hip/hip_bf16.h>

#define NB 4096
#define MB 1024
#define SZ ((size_t)MB * NB)
#define NN ((size_t)NB * NB)

typedef __bf16 bf16_t;
typedef __attribute__((ext_vector_type(8))) __bf16 bf16x8;
typedef __attribute__((ext_vector_type(4))) float f32x4;
typedef __attribute__((ext_vector_type(4))) unsigned int u32x4;

#define AS1 __attribute__((address_space(1)))
#define AS3 __attribute__((address_space(3)))
#define GLOAD16(gp, lp)                                                        \
  __builtin_amdgcn_global_load_lds((const AS1 unsigned int*)(gp),              \
                                   (AS3 unsigned int*)(lp), 16, 0, 0)
#define SBAR() __builtin_amdgcn_s_barrier()
#define SCHEDB() __builtin_amdgcn_sched_barrier(0)
#define MFMA16(a, b, c) __builtin_amdgcn_mfma_f32_16x16x32_bf16((a), (b), (c), 0, 0, 0)

// Half-K-tile LDS layout: [rows][32 k] bf16, 4 cells of 8 bf16 per row.
// cell (r, c) stored at slot s = c ^ (r&3). gload_lds writes linearly
// (lane l -> row base+(l>>2), slot l&3) with pre-swizzled global source
// chunk c = (l&3) ^ ((l>>2)&3). Read of k-chunk kq at row R: slot kq^(R&3);
// for frag reads R&3 == lr&3 -> per-lane constant kswz. 2-way bank alias max.

__device__ __forceinline__ bf16x8 neg8(bf16x8 x) {
  u32x4 t;
  __builtin_memcpy(&t, &x, 16);
  t ^= 0x80008000u;
  bf16x8 y;
  __builtin_memcpy(&y, &t, 16);
  return y;
}

__device__ __forceinline__ bf16x8 cvt8(float4 a, float4 b) {
  bf16x8 v;
  v[0] = (bf16_t)a.x; v[1] = (bf16_t)a.y; v[2] = (bf16_t)a.z; v[3] = (bf16_t)a.w;
  v[4] = (bf16_t)b.x; v[5] = (bf16_t)b.y; v[6] = (bf16_t)b.z; v[7] = (bf16_t)b.w;
  return v;
}

// ---------------- prep: f32 -> bf16 ----------------
#define ITEM_S (SZ / 8)
#define ITEM_N (NN / 8)

__global__ __launch_bounds__(256) void prep6_kernel(
    const float* __restrict__ u, const float* __restrict__ w,
    const float* __restrict__ G, const float* __restrict__ Bm,
    const float* __restrict__ Wp, const float* __restrict__ Wq,
    bf16_t* __restrict__ ws) {
  size_t stride = (size_t)gridDim.x * blockDim.x;
  const size_t tot = 2 * ITEM_S + 4 * ITEM_N;
  for (size_t i = (size_t)blockIdx.x * blockDim.x + threadIdx.x; i < tot;
       i += stride) {
    const float* src;
    bf16_t* dst;
    size_t off;
    if (i < ITEM_S) { src = u; dst = ws; off = i; }
    else if (i < 2 * ITEM_S) { src = w; dst = ws + SZ; off = i - ITEM_S; }
    else if (i < 2 * ITEM_S + ITEM_N) { src = G; dst = ws + 2 * SZ; off = i - 2 * ITEM_S; }
    else if (i < 2 * ITEM_S + 2 * ITEM_N) { src = Bm; dst = ws + 2 * SZ + NN; off = i - 2 * ITEM_S - ITEM_N; }
    else if (i < 2 * ITEM_S + 3 * ITEM_N) { src = Wp; dst = ws + 2 * SZ + 2 * NN; off = i - 2 * ITEM_S - 2 * ITEM_N; }
    else { src = Wq; dst = ws + 2 * SZ + 3 * NN; off = i - 2 * ITEM_S - 3 * ITEM_N; }
    const float4* s = reinterpret_cast<const float4*>(src) + off * 2;
    reinterpret_cast<bf16x8*>(dst)[off] = cvt8(s[0], s[1]);
  }
}

__global__ __launch_bounds__(256) void prep4_kernel(
    const float* __restrict__ u, const float* __restrict__ w,
    const float* __restrict__ G, const float* __restrict__ Bm,
    bf16_t* __restrict__ ws) {
  size_t stride = (size_t)gridDim.x * blockDim.x;
  const size_t tot = 2 * ITEM_S + 2 * ITEM_N;
  for (size_t i = (size_t)blockIdx.x * blockDim.x + threadIdx.x; i < tot;
       i += stride) {
    const float* src;
    bf16_t* dst;
    size_t off;
    if (i < ITEM_S) { src = u; dst = ws; off = i; }
    else if (i < 2 * ITEM_S) { src = w; dst = ws + SZ; off = i - ITEM_S; }
    else if (i < 2 * ITEM_S + ITEM_N) { src = G; dst = ws + 2 * SZ; off = i - 2 * ITEM_S; }
    else { src = Bm; dst = ws + 2 * SZ + NN; off = i - 2 * ITEM_S - ITEM_N; }
    const float4* s = reinterpret_cast<const float4*>(src) + off * 2;
    reinterpret_cast<bf16x8*>(dst)[off] = cvt8(s[0], s[1]);
  }
}

// ---------------- fused stage 1, counted-vmcnt ring pipeline ----------------
// S = u@G^T - w@B^T, T = w@G^T + u@B^T; p_mid/q_mid epilogue.
// Tile 128x128, 8 waves (2m x 4n, wave 64x32). K-halves of 32; ring of 4
// half-slots per operand (128 KB). Per wave per half: 4 gload_lds.
// Steady-state wait: vmcnt(8) (= 2 halves in flight); tail 4 -> 0.
__global__ __launch_bounds__(512, 2) void fused1_v4(
    const float* __restrict__ u, const float* __restrict__ w,
    const bf16_t* __restrict__ ubf, const bf16_t* __restrict__ wbf,
    const bf16_t* __restrict__ Gbf, const bf16_t* __restrict__ Bbf,
    const float* __restrict__ bias_p, const float* __restrict__ bias_q,
    bf16_t* __restrict__ pq) {
  __shared__ bf16_t lds[4][4][128 * 32];  // [slot][op][row*32] = 128 KB
  const int tid = threadIdx.x, lane = tid & 63, wv = tid >> 6;
  const int bid = blockIdx.x;
  const int t = (bid & 7) * 32 + (bid >> 3);  // XCD swizzle, 256 blocks
  const int row0 = (t & 7) * 128, col0 = (t >> 3) * 128;
  const int wm = (wv >> 2) * 64, wn = (wv & 3) * 32;
  const int lr = lane & 15, kq = lane >> 4;
  const int kswz = (kq ^ (lr & 3)) << 3;

  const int srow = wv * 16 + (lane >> 2);
  const int sc = (lane & 3) ^ ((lane >> 2) & 3);
  const bf16_t* gsrc[4];
  gsrc[0] = ubf + (size_t)(row0 + srow) * NB + sc * 8;
  gsrc[1] = wbf + (size_t)(row0 + srow) * NB + sc * 8;
  gsrc[2] = Gbf + (size_t)(col0 + srow) * NB + sc * 8;
  gsrc[3] = Bbf + (size_t)(col0 + srow) * NB + sc * 8;

#define F1_ISS(op, sl, ko) GLOAD16(gsrc[op] + (ko), &lds[sl][op][wv * 512])

  int aoff[4], boff[2];
#pragma unroll
  for (int m = 0; m < 4; ++m) aoff[m] = (wm + m * 16 + lr) * 32 + kswz;
#pragma unroll
  for (int n = 0; n < 2; ++n) boff[n] = (wn + n * 16 + lr) * 32 + kswz;

  f32x4 aS[4][2] = {}, aT[4][2] = {};

  // prologue: issue halves 0,1,2
#pragma unroll
  for (int hh = 0; hh < 3; ++hh) {
    F1_ISS(0, hh, hh * 32);
    F1_ISS(1, hh, hh * 32);
    F1_ISS(2, hh, hh * 32);
    F1_ISS(3, hh, hh * 32);
  }
  asm volatile("s_waitcnt vmcnt(8)" ::: "memory");  // half 0 landed
  SBAR();
  SCHEDB();

  const int HTOT = 2 * (NB / 64);  // 128 halves
  for (int h = 0; h < HTOT; ++h) {
    const int slot = h & 3;
    const bool pf = (h + 3) < HTOT;
    const int pslot = (h + 3) & 3;
    const int pko = (h + 3) * 32;

    // ---- phase A (m-half 0): B-frags + A-frags m0,m1 ----
    bf16x8 bG[2], bB[2], bBn[2], au2[2], aw2[2];
#pragma unroll
    for (int n = 0; n < 2; ++n) {
      bG[n] = *reinterpret_cast<const bf16x8*>(&lds[slot][2][boff[n]]);
      bB[n] = *reinterpret_cast<const bf16x8*>(&lds[slot][3][boff[n]]);
    }
    bBn[0] = neg8(bB[0]);
    bBn[1] = neg8(bB[1]);
#pragma unroll
    for (int i = 0; i < 2; ++i) {
      au2[i] = *reinterpret_cast<const bf16x8*>(&lds[slot][0][aoff[i]]);
      aw2[i] = *reinterpret_cast<const bf16x8*>(&lds[slot][1][aoff[i]]);
    }
    if (pf) { F1_ISS(0, pslot, pko); F1_ISS(1, pslot, pko); }
    SBAR();
    SCHEDB();
    __builtin_amdgcn_s_setprio(1);
#pragma unroll
    for (int i = 0; i < 2; ++i)
#pragma unroll
      for (int n = 0; n < 2; ++n) {
        aS[i][n] = MFMA16(au2[i], bG[n], aS[i][n]);
        aS[i][n] = MFMA16(aw2[i], bBn[n], aS[i][n]);
        aT[i][n] = MFMA16(aw2[i], bG[n], aT[i][n]);
        aT[i][n] = MFMA16(au2[i], bB[n], aT[i][n]);
      }
    __builtin_amdgcn_s_setprio(0);
    SCHEDB();
    SBAR();
    SCHEDB();

    // ---- phase B (m-half 1): A-frags m2,m3 ----
#pragma unroll
    for (int i = 0; i < 2; ++i) {
      au2[i] = *reinterpret_cast<const bf16x8*>(&lds[slot][0][aoff[2 + i]]);
      aw2[i] = *reinterpret_cast<const bf16x8*>(&lds[slot][1][aoff[2 + i]]);
    }
    if (pf) { F1_ISS(2, pslot, pko); F1_ISS(3, pslot, pko); }
    SBAR();
    SCHEDB();
    __builtin_amdgcn_s_setprio(1);
#pragma unroll
    for (int i = 0; i < 2; ++i) {
      const int m = 2 + i;
#pragma unroll
      for (int n = 0; n < 2; ++n) {
        aS[m][n] = MFMA16(au2[i], bG[n], aS[m][n]);
        aS[m][n] = MFMA16(aw2[i], bBn[n], aS[m][n]);
        aT[m][n] = MFMA16(aw2[i], bG[n], aT[m][n]);
        aT[m][n] = MFMA16(au2[i], bB[n], aT[m][n]);
      }
    }
    __builtin_amdgcn_s_setprio(0);
    SCHEDB();
    // counted wait: next half's loads must have landed; keep 2 halves in flight
    if (h < HTOT - 3)
      asm volatile("s_waitcnt vmcnt(8)" ::: "memory");
    else if (h == HTOT - 3)
      asm volatile("s_waitcnt vmcnt(4)" ::: "memory");
    else if (h == HTOT - 2)
      asm volatile("s_waitcnt vmcnt(0)" ::: "memory");
    SBAR();
    SCHEDB();
  }

  // epilogue: combine with u,w (f32) + biases -> p_mid/q_mid bf16
  const int fr = lane & 15, fq = kq;
#pragma unroll
  for (int m = 0; m < 4; ++m)
#pragma unroll
    for (int n = 0; n < 2; ++n)
#pragma unroll
      for (int j = 0; j < 4; ++j) {
        int r = row0 + wm + m * 16 + fq * 4 + j;
        int c = col0 + wn + n * 16 + fr;
        size_t idx = (size_t)r * NB + c;
        float U = u[idx], W = w[idx];
        float S = aS[m][n][j], T = aT[m][n][j];
        pq[idx] = (bf16_t)(U * S + W * T + bias_p[c]);
        pq[SZ + idx] = (bf16_t)(W * S - U * T + bias_q[c]);
      }
}

// ---------------- stage 2, counted-vmcnt ring pipeline ----------------
// out_z = pq_z @ W_z^T + b_z (f32). Tile 128(M)x256(N), 8 waves (2m x 4n,
// wave 64x64). Ring of 4 half-slots (A 32 KB + W 64 KB). Per wave per half:
// 3 gload_lds (1 A + 2 W). Steady wait vmcnt(6); tail 3 -> 0.
__global__ __launch_bounds__(512, 2) void gemm2_v5(
    const bf16_t* __restrict__ pq, const bf16_t* __restrict__ Wpb,
    const bf16_t* __restrict__ Wqb, const float* __restrict__ bp,
    const float* __restrict__ bq, float* __restrict__ out) {
  __shared__ bf16_t lA[4][128 * 32];  // 32 KB
  __shared__ bf16_t lW[4][256 * 32];  // 64 KB
  const int tid = threadIdx.x, lane = tid & 63, wv = tid >> 6;
  const int bid = blockIdx.x;
  const int t = (bid & 7) * 32 + (bid >> 3);  // XCD swizzle, 256 blocks
  const int z = t >> 7;
  const int s = t & 127;
  const int row0 = (s & 7) * 128, col0 = (s >> 3) * 256;

  const bf16_t* A = pq + (size_t)z * SZ;
  const bf16_t* Wm = z ? Wqb : Wpb;
  const float* bias = z ? bq : bp;
  float* C = out + (size_t)z * SZ;

  const int wm = (wv >> 2) * 64, wn = (wv & 3) * 64;
  const int lr = lane & 15, kq = lane >> 4;
  const int kswz = (kq ^ (lr & 3)) << 3;

  const int srow = lane >> 2;
  const int sc = (lane & 3) ^ ((lane >> 2) & 3);
  const bf16_t* gA0 = A + (size_t)(row0 + wv * 16 + srow) * NB + sc * 8;
  const bf16_t* gW0 = Wm + (size_t)(col0 + wv * 32 + srow) * NB + sc * 8;
  const bf16_t* gW1 = gW0 + (size_t)16 * NB;

#define G2_ISS(sl, ko)                                                         \
  do {                                                                         \
    GLOAD16(gA0 + (ko), &lA[sl][wv * 512]);                                    \
    GLOAD16(gW0 + (ko), &lW[sl][wv * 1024]);                                   \
    GLOAD16(gW1 + (ko), &lW[sl][wv * 1024 + 512]);                             \
  } while (0)

  int aoff[4], woff[4];
#pragma unroll
  for (int m = 0; m < 4; ++m) aoff[m] = (wm + m * 16 + lr) * 32 + kswz;
#pragma unroll
  for (int n = 0; n < 4; ++n) woff[n] = (wn + n * 16 + lr) * 32 + kswz;

  f32x4 acc[4][4] = {};

#pragma unroll
  for (int hh = 0; hh < 3; ++hh) G2_ISS(hh, hh * 32);
  asm volatile("s_waitcnt vmcnt(6)" ::: "memory");
  SBAR();
  SCHEDB();

  const int HTOT = 2 * (NB / 64);
  for (int h = 0; h < HTOT; ++h) {
    const int slot = h & 3;
    const bool pf = (h + 3) < HTOT;
    const int pslot = (h + 3) & 3;
    const int pko = (h + 3) * 32;

    bf16x8 av[4], bw[4];
#pragma unroll
    for (int m = 0; m < 4; ++m)
      av[m] = *reinterpret_cast<const bf16x8*>(&lA[slot][aoff[m]]);
#pragma unroll
    for (int n = 0; n < 4; ++n)
      bw[n] = *reinterpret_cast<const bf16x8*>(&lW[slot][woff[n]]);
    if (pf) G2_ISS(pslot, pko);
    SBAR();
    SCHEDB();
    __builtin_amdgcn_s_setprio(1);
#pragma unroll
    for (int m = 0; m < 4; ++m)
#pragma unroll
      for (int n = 0; n < 4; ++n)
        acc[m][n] = MFMA16(av[m], bw[n], acc[m][n]);
    __builtin_amdgcn_s_setprio(0);
    SCHEDB();
    if (h < HTOT - 3)
      asm volatile("s_waitcnt vmcnt(6)" ::: "memory");
    else if (h == HTOT - 3)
      asm volatile("s_waitcnt vmcnt(3)" ::: "memory");
    else if (h == HTOT - 2)
      asm volatile("s_waitcnt vmcnt(0)" ::: "memory");
    SBAR();
    SCHEDB();
  }

  const int fr = lane & 15, fq = kq;
#pragma unroll
  for (int m = 0; m < 4; ++m)
#pragma unroll
    for (int n = 0; n < 4; ++n)
#pragma unroll
      for (int j = 0; j < 4; ++j) {
        int r = row0 + wm + m * 16 + fq * 4 + j;
        int c = col0 + wn + n * 16 + fr;
        C[(size_t)r * NB + c] = acc[m][n][j] + bias[c];
      }
}

// ---------------- fallbacks (compile-only safety net) ----------------
__device__ __forceinline__ int swz_off32(int r, int kk) {
  return r * 32 + ((kk ^ ((r >> 1) & 3)) << 3);
}

__device__ __forceinline__ void fb_stage_f32(const float* __restrict__ src,
                                             int row0, int k0, bf16_t* lds, int t) {
  int r = t >> 2, kk = t & 3;
  const float* p = src + (size_t)(row0 + r) * NB + k0 + (kk << 3);
  float4 v0 = *reinterpret_cast<const float4*>(p);
  float4 v1 = *reinterpret_cast<const float4*>(p + 4);
  *reinterpret_cast<bf16x8*>(lds + swz_off32(r, kk)) = cvt8(v0, v1);
}

__global__ __launch_bounds__(256, 2) void fb_gemm2(
    const bf16_t* __restrict__ pq, const float* __restrict__ Wp,
    const float* __restrict__ Wq, const float* __restrict__ bp,
    const float* __restrict__ bq, float* __restrict__ out) {
  __shared__ bf16_t lA[128 * 32], lW[128 * 32];
  const int z = blockIdx.z;
  const bf16_t* A = pq + (size_t)z * SZ;
  const float* Wm = z ? Wq : Wp;
  const float* bias = z ? bq : bp;
  float* C = out + (size_t)z * SZ;
  const int tid = threadIdx.x;
  const int lane = tid & 63, wv = tid >> 6;
  const int wm = (wv >> 1) * 64, wn = (wv & 1) * 64;
  const int row0 = blockIdx.y * 128, col0 = blockIdx.x * 128;
  const int lr = lane & 15, kq = lane >> 4;
  const int fslot = (kq ^ ((lr >> 1) & 3)) << 3;
  f32x4 acc[4][4] = {};
  for (int kt = 0; kt < NB; kt += 32) {
#pragma unroll
    for (int p = 0; p < 2; ++p) {
      int cb = p * 256 + wv * 64;
      int ci = cb + lane;
      int r = ci >> 2, kl = ci & 3;
      int ks = kl ^ ((r >> 1) & 3);
      const bf16_t* g = A + (size_t)(row0 + r) * NB + kt + (ks << 3);
      GLOAD16(g, lA + cb * 8);
    }
#pragma unroll
    for (int p = 0; p < 2; ++p)
      fb_stage_f32(Wm, col0, kt, lW, p * 256 + tid);
    __syncthreads();
    bf16x8 af[4], bg[4];
#pragma unroll
    for (int m = 0; m < 4; ++m)
      af[m] = *reinterpret_cast<const bf16x8*>(lA + (wm + m * 16 + lr) * 32 + fslot);
#pragma unroll
    for (int n = 0; n < 4; ++n)
      bg[n] = *reinterpret_cast<const bf16x8*>(lW + (wn + n * 16 + lr) * 32 + fslot);
#pragma unroll
    for (int m = 0; m < 4; ++m)
#pragma unroll
      for (int n = 0; n < 4; ++n)
        acc[m][n] = MFMA16(af[m], bg[n], acc[m][n]);
    __syncthreads();
  }
  const int fr = lane & 15, fq = lane >> 4;
#pragma unroll
  for (int m = 0; m < 4; ++m)
#pragma unroll
    for (int n = 0; n < 4; ++n)
#pragma unroll
      for (int j = 0; j < 4; ++j) {
        int r = row0 + wm + m * 16 + fq * 4 + j;
        int c = col0 + wn + n * 16 + fr;
        C[(size_t)r * NB + c] = acc[m][n][j] + bias[c];
      }
}

__global__ __launch_bounds__(512, 2) void fb_fused1(
    const float* __restrict__ u, const float* __restrict__ w,
    const float* __restrict__ G, const float* __restrict__ Bm,
    const float* __restrict__ bias_p, const float* __restrict__ bias_q,
    bf16_t* __restrict__ pq) {
  __shared__ bf16_t lU[128 * 32], lW[128 * 32], lG[128 * 32], lB[128 * 32];
  const int tid = threadIdx.x;
  const int lane = tid & 63, wv = tid >> 6;
  const int wm = (wv >> 2) * 64, wn = (wv & 3) * 32;
  const int row0 = blockIdx.y * 128, col0 = blockIdx.x * 128;
  const int lr = lane & 15, kq = lane >> 4;
  const int fslot = (kq ^ ((lr >> 1) & 3)) << 3;
  f32x4 aS[4][2] = {}, aT[4][2] = {};
  for (int kt = 0; kt < NB; kt += 32) {
    fb_stage_f32(u, row0, kt, lU, tid);
    fb_stage_f32(w, row0, kt, lW, tid);
    fb_stage_f32(G, col0, kt, lG, tid);
    fb_stage_f32(Bm, col0, kt, lB, tid);
    __syncthreads();
    bf16x8 au[4], aw[4], bG[2], bB[2], bBn[2];
#pragma unroll
    for (int m = 0; m < 4; ++m) {
      int off = (wm + m * 16 + lr) * 32 + fslot;
      au[m] = *reinterpret_cast<const bf16x8*>(lU + off);
      aw[m] = *reinterpret_cast<const bf16x8*>(lW + off);
    }
#pragma unroll
    for (int n = 0; n < 2; ++n) {
      int off = (wn + n * 16 + lr) * 32 + fslot;
      bG[n] = *reinterpret_cast<const bf16x8*>(lG + off);
      bB[n] = *reinterpret_cast<const bf16x8*>(lB + off);
      bBn[n] = neg8(bB[n]);
    }
#pragma unroll
    for (int m = 0; m < 4; ++m)
#pragma unroll
      for (int n = 0; n < 2; ++n) {
        aS[m][n] = MFMA16(au[m], bG[n], aS[m][n]);
        aS[m][n] = MFMA16(aw[m], bBn[n], aS[m][n]);
        aT[m][n] = MFMA16(aw[m], bG[n], aT[m][n]);
        aT[m][n] = MFMA16(au[m], bB[n], aT[m][n]);
      }
    __syncthreads();
  }
  const int fr = lane & 15, fq = lane >> 4;
#pragma unroll
  for (int m = 0; m < 4; ++m)
#pragma unroll
    for (int n = 0; n < 2; ++n)
#pragma unroll
      for (int j = 0; j < 4; ++j) {
        int r = row0 + wm + m * 16 + fq * 4 + j;
        int c = col0 + wn + n * 16 + fr;
        size_t idx = (size_t)r * NB + c;
        float U = u[idx], W = w[idx];
        float S = aS[m][n][j], T = aT[m][n][j];
        pq[idx] = (bf16_t)(U * S + W * T + bias_p[c]);
        pq[SZ + idx] = (bf16_t)(W * S - U * T + bias_q[c]);
      }
}

extern "C" void kernel_launch(void* const* d_in, const int* in_sizes, int n_in,
                              void* d_out, int out_size, void* d_ws, size_t ws_size,
                              hipStream_t stream) {
  const float* u = (const float*)d_in[0];
  const float* w = (const float*)d_in[1];
  const float* G = (const float*)d_in[2];
  const float* Bm = (const float*)d_in[3];
  const float* bias_p = (const float*)d_in[4];
  const float* bias_q = (const float*)d_in[5];
  const float* Wp = (const float*)d_in[6];
  const float* bp = (const float*)d_in[7];
  const float* Wq = (const float*)d_in[8];
  const float* bq = (const float*)d_in[9];
  (void)in_sizes; (void)n_in; (void)out_size;

  const size_t need_full = (6 * SZ + 4 * NN) * sizeof(bf16_t);  // 176 MB
  const size_t need_mid = (6 * SZ + 2 * NN) * sizeof(bf16_t);   // 112 MB

  if (ws_size >= need_full) {
    bf16_t* ws = (bf16_t*)d_ws;
    bf16_t* ubf = ws;
    bf16_t* wbf = ws + SZ;
    bf16_t* Gbf = ws + 2 * SZ;
    bf16_t* Bbf = Gbf + NN;
    bf16_t* Wpb = Bbf + NN;
    bf16_t* Wqb = Wpb + NN;
    bf16_t* pqw = Wqb + NN;
    prep6_kernel<<<2048, 256, 0, stream>>>(u, w, G, Bm, Wp, Wq, ws);
    fused1_v4<<<256, 512, 0, stream>>>(u, w, ubf, wbf, Gbf, Bbf,
                                       bias_p, bias_q, pqw);
    gemm2_v5<<<256, 512, 0, stream>>>(pqw, Wpb, Wqb, bp, bq, (float*)d_out);
  } else if (ws_size >= need_mid) {
    bf16_t* ws = (bf16_t*)d_ws;
    bf16_t* ubf = ws;
    bf16_t* wbf = ws + SZ;
    bf16_t* Gbf = ws + 2 * SZ;
    bf16_t* Bbf = Gbf + NN;
    bf16_t* pqw = Bbf + NN;
    prep4_kernel<<<2048, 256, 0, stream>>>(u, w, G, Bm, ws);
    fused1_v4<<<256, 512, 0, stream>>>(u, w, ubf, wbf, Gbf, Bbf,
                                       bias_p, bias_q, pqw);
    fb_gemm2<<<dim3(NB / 128, MB / 128, 2), 256, 0, stream>>>(
        pqw, Wp, Wq, bp, bq, (float*)d_out);
  } else {
    bf16_t* pqw = (bf16_t*)d_ws;
    fb_fused1<<<dim3(NB / 128, MB / 128), 512, 0, stream>>>(
        u, w, G, Bm, bias_p, bias_q, pqw);
    fb_gemm2<<<dim3(NB / 128, MB / 128, 2), 256, 0, stream>>>(
        pqw, Wp, Wq, bp, bq, (float*)d_out);
  }
}

// Round 7
// 318.050 us; speedup vs baseline: 1.5380x; 1.0084x over previous
//
#include <hip/hip_runtime.h>
#include <hip/hip_bf16.h>

#define NB 4096
#define MB 1024
#define SZ ((size_t)MB * NB)
#define NN ((size_t)NB * NB)

typedef __bf16 bf16_t;
typedef __attribute__((ext_vector_type(8))) __bf16 bf16x8;
typedef __attribute__((ext_vector_type(4))) float f32x4;
typedef __attribute__((ext_vector_type(4))) unsigned int u32x4;

#define AS1 __attribute__((address_space(1)))
#define AS3 __attribute__((address_space(3)))
#define GLOAD16(gp, lp)                                                        \
  __builtin_amdgcn_global_load_lds((const AS1 unsigned int*)(gp),              \
                                   (AS3 unsigned int*)(lp), 16, 0, 0)
#define SBAR() __builtin_amdgcn_s_barrier()
#define SCHEDB() __builtin_amdgcn_sched_barrier(0)
#define MFMA16(a, b, c) __builtin_amdgcn_mfma_f32_16x16x32_bf16((a), (b), (c), 0, 0, 0)

// Half-K-tile LDS layout: [rows][32 k] bf16, 4 cells of 8 bf16 (16B) per row.
// cell (r, c) stored at slot s = c ^ ((r>>1)&3)  [decorrelated from row
// parity: 16 lanes reading fixed k-chunk across rows 16a+lr hit all 8
// (parity x slot) bank groups x2 lanes = bank-uniform floor].
// gload_lds writes linearly (lane l -> row base+(l>>2), slot l&3); global
// source pre-swizzled: chunk c = (l&3) ^ ((l>>3)&3)  (bases are multiples
// of 8 rows). Read of k-chunk kq at row R=16a+lr: slot kq^((lr>>1)&3).

__device__ __forceinline__ bf16x8 neg8(bf16x8 x) {
  u32x4 t;
  __builtin_memcpy(&t, &x, 16);
  t ^= 0x80008000u;
  bf16x8 y;
  __builtin_memcpy(&y, &t, 16);
  return y;
}

__device__ __forceinline__ bf16x8 cvt8(float4 a, float4 b) {
  bf16x8 v;
  v[0] = (bf16_t)a.x; v[1] = (bf16_t)a.y; v[2] = (bf16_t)a.z; v[3] = (bf16_t)a.w;
  v[4] = (bf16_t)b.x; v[5] = (bf16_t)b.y; v[6] = (bf16_t)b.z; v[7] = (bf16_t)b.w;
  return v;
}

// ---------------- prep: f32 -> bf16 ----------------
#define ITEM_S (SZ / 8)
#define ITEM_N (NN / 8)

__global__ __launch_bounds__(256) void prep6_kernel(
    const float* __restrict__ u, const float* __restrict__ w,
    const float* __restrict__ G, const float* __restrict__ Bm,
    const float* __restrict__ Wp, const float* __restrict__ Wq,
    bf16_t* __restrict__ ws) {
  size_t stride = (size_t)gridDim.x * blockDim.x;
  const size_t tot = 2 * ITEM_S + 4 * ITEM_N;
  for (size_t i = (size_t)blockIdx.x * blockDim.x + threadIdx.x; i < tot;
       i += stride) {
    const float* src;
    bf16_t* dst;
    size_t off;
    if (i < ITEM_S) { src = u; dst = ws; off = i; }
    else if (i < 2 * ITEM_S) { src = w; dst = ws + SZ; off = i - ITEM_S; }
    else if (i < 2 * ITEM_S + ITEM_N) { src = G; dst = ws + 2 * SZ; off = i - 2 * ITEM_S; }
    else if (i < 2 * ITEM_S + 2 * ITEM_N) { src = Bm; dst = ws + 2 * SZ + NN; off = i - 2 * ITEM_S - ITEM_N; }
    else if (i < 2 * ITEM_S + 3 * ITEM_N) { src = Wp; dst = ws + 2 * SZ + 2 * NN; off = i - 2 * ITEM_S - 2 * ITEM_N; }
    else { src = Wq; dst = ws + 2 * SZ + 3 * NN; off = i - 2 * ITEM_S - 3 * ITEM_N; }
    const float4* s = reinterpret_cast<const float4*>(src) + off * 2;
    reinterpret_cast<bf16x8*>(dst)[off] = cvt8(s[0], s[1]);
  }
}

__global__ __launch_bounds__(256) void prep4_kernel(
    const float* __restrict__ u, const float* __restrict__ w,
    const float* __restrict__ G, const float* __restrict__ Bm,
    bf16_t* __restrict__ ws) {
  size_t stride = (size_t)gridDim.x * blockDim.x;
  const size_t tot = 2 * ITEM_S + 2 * ITEM_N;
  for (size_t i = (size_t)blockIdx.x * blockDim.x + threadIdx.x; i < tot;
       i += stride) {
    const float* src;
    bf16_t* dst;
    size_t off;
    if (i < ITEM_S) { src = u; dst = ws; off = i; }
    else if (i < 2 * ITEM_S) { src = w; dst = ws + SZ; off = i - ITEM_S; }
    else if (i < 2 * ITEM_S + ITEM_N) { src = G; dst = ws + 2 * SZ; off = i - 2 * ITEM_S; }
    else { src = Bm; dst = ws + 2 * SZ + NN; off = i - 2 * ITEM_S - ITEM_N; }
    const float4* s = reinterpret_cast<const float4*>(src) + off * 2;
    reinterpret_cast<bf16x8*>(dst)[off] = cvt8(s[0], s[1]);
  }
}

// ---------------- fused stage 1, counted-vmcnt ring pipeline ----------------
// S = u@G^T - w@B^T, T = w@G^T + u@B^T; p_mid/q_mid epilogue.
// Tile 128x128, 8 waves (2m x 4n, wave 64x32). K-halves of 32; ring of 4
// half-slots per operand (128 KB). Per wave per half: 4 gload_lds.
// Steady-state wait: vmcnt(8) (= 2 halves in flight); tail 4 -> 0.
__global__ __launch_bounds__(512, 2) void fused1_v5(
    const float* __restrict__ u, const float* __restrict__ w,
    const bf16_t* __restrict__ ubf, const bf16_t* __restrict__ wbf,
    const bf16_t* __restrict__ Gbf, const bf16_t* __restrict__ Bbf,
    const float* __restrict__ bias_p, const float* __restrict__ bias_q,
    bf16_t* __restrict__ pq) {
  __shared__ bf16_t lds[4][4][128 * 32];  // [slot][op][row*32] = 128 KB
  const int tid = threadIdx.x, lane = tid & 63, wv = tid >> 6;
  const int bid = blockIdx.x;
  const int t = (bid & 7) * 32 + (bid >> 3);  // XCD swizzle, 256 blocks
  const int row0 = (t & 7) * 128, col0 = (t >> 3) * 128;
  const int wm = (wv >> 2) * 64, wn = (wv & 3) * 32;
  const int lr = lane & 15, kq = lane >> 4;
  const int kswz = (kq ^ ((lr >> 1) & 3)) << 3;

  const int srow = wv * 16 + (lane >> 2);
  const int sc = (lane & 3) ^ ((lane >> 3) & 3);
  const bf16_t* gsrc[4];
  gsrc[0] = ubf + (size_t)(row0 + srow) * NB + sc * 8;
  gsrc[1] = wbf + (size_t)(row0 + srow) * NB + sc * 8;
  gsrc[2] = Gbf + (size_t)(col0 + srow) * NB + sc * 8;
  gsrc[3] = Bbf + (size_t)(col0 + srow) * NB + sc * 8;

#define F1_ISS(op, sl, ko) GLOAD16(gsrc[op] + (ko), &lds[sl][op][wv * 512])

  int aoff[4], boff[2];
#pragma unroll
  for (int m = 0; m < 4; ++m) aoff[m] = (wm + m * 16 + lr) * 32 + kswz;
#pragma unroll
  for (int n = 0; n < 2; ++n) boff[n] = (wn + n * 16 + lr) * 32 + kswz;

  f32x4 aS[4][2] = {}, aT[4][2] = {};

  // prologue: issue halves 0,1,2
#pragma unroll
  for (int hh = 0; hh < 3; ++hh) {
    F1_ISS(0, hh, hh * 32);
    F1_ISS(1, hh, hh * 32);
    F1_ISS(2, hh, hh * 32);
    F1_ISS(3, hh, hh * 32);
  }
  asm volatile("s_waitcnt vmcnt(8)" ::: "memory");  // half 0 landed
  SBAR();
  SCHEDB();

  const int HTOT = 2 * (NB / 64);  // 128 halves
  for (int h = 0; h < HTOT; ++h) {
    const int slot = h & 3;
    const bool pf = (h + 3) < HTOT;
    const int pslot = (h + 3) & 3;
    const int pko = (h + 3) * 32;

    // ---- phase A (m-half 0): B-frags + A-frags m0,m1 ----
    bf16x8 bG[2], bB[2], bBn[2], au2[2], aw2[2];
#pragma unroll
    for (int n = 0; n < 2; ++n) {
      bG[n] = *reinterpret_cast<const bf16x8*>(&lds[slot][2][boff[n]]);
      bB[n] = *reinterpret_cast<const bf16x8*>(&lds[slot][3][boff[n]]);
    }
    bBn[0] = neg8(bB[0]);
    bBn[1] = neg8(bB[1]);
#pragma unroll
    for (int i = 0; i < 2; ++i) {
      au2[i] = *reinterpret_cast<const bf16x8*>(&lds[slot][0][aoff[i]]);
      aw2[i] = *reinterpret_cast<const bf16x8*>(&lds[slot][1][aoff[i]]);
    }
    if (pf) { F1_ISS(0, pslot, pko); F1_ISS(1, pslot, pko); }
    SBAR();
    SCHEDB();
    __builtin_amdgcn_s_setprio(1);
#pragma unroll
    for (int i = 0; i < 2; ++i)
#pragma unroll
      for (int n = 0; n < 2; ++n) {
        aS[i][n] = MFMA16(au2[i], bG[n], aS[i][n]);
        aS[i][n] = MFMA16(aw2[i], bBn[n], aS[i][n]);
        aT[i][n] = MFMA16(aw2[i], bG[n], aT[i][n]);
        aT[i][n] = MFMA16(au2[i], bB[n], aT[i][n]);
      }
    __builtin_amdgcn_s_setprio(0);
    SCHEDB();
    SBAR();
    SCHEDB();

    // ---- phase B (m-half 1): A-frags m2,m3 ----
#pragma unroll
    for (int i = 0; i < 2; ++i) {
      au2[i] = *reinterpret_cast<const bf16x8*>(&lds[slot][0][aoff[2 + i]]);
      aw2[i] = *reinterpret_cast<const bf16x8*>(&lds[slot][1][aoff[2 + i]]);
    }
    if (pf) { F1_ISS(2, pslot, pko); F1_ISS(3, pslot, pko); }
    SBAR();
    SCHEDB();
    __builtin_amdgcn_s_setprio(1);
#pragma unroll
    for (int i = 0; i < 2; ++i) {
      const int m = 2 + i;
#pragma unroll
      for (int n = 0; n < 2; ++n) {
        aS[m][n] = MFMA16(au2[i], bG[n], aS[m][n]);
        aS[m][n] = MFMA16(aw2[i], bBn[n], aS[m][n]);
        aT[m][n] = MFMA16(aw2[i], bG[n], aT[m][n]);
        aT[m][n] = MFMA16(au2[i], bB[n], aT[m][n]);
      }
    }
    __builtin_amdgcn_s_setprio(0);
    SCHEDB();
    // counted wait: next half's loads must have landed; keep 2 halves in flight
    if (h < HTOT - 3)
      asm volatile("s_waitcnt vmcnt(8)" ::: "memory");
    else if (h == HTOT - 3)
      asm volatile("s_waitcnt vmcnt(4)" ::: "memory");
    else if (h == HTOT - 2)
      asm volatile("s_waitcnt vmcnt(0)" ::: "memory");
    SBAR();
    SCHEDB();
  }

  // epilogue: combine with u,w (f32) + biases -> p_mid/q_mid bf16
  const int fr = lane & 15, fq = kq;
#pragma unroll
  for (int m = 0; m < 4; ++m)
#pragma unroll
    for (int n = 0; n < 2; ++n)
#pragma unroll
      for (int j = 0; j < 4; ++j) {
        int r = row0 + wm + m * 16 + fq * 4 + j;
        int c = col0 + wn + n * 16 + fr;
        size_t idx = (size_t)r * NB + c;
        float U = u[idx], W = w[idx];
        float S = aS[m][n][j], T = aT[m][n][j];
        pq[idx] = (bf16_t)(U * S + W * T + bias_p[c]);
        pq[SZ + idx] = (bf16_t)(W * S - U * T + bias_q[c]);
      }
}

// ---------------- stage 2, counted-vmcnt ring pipeline ----------------
// out_z = pq_z @ W_z^T + b_z (f32). Tile 128(M)x256(N), 8 waves (2m x 4n,
// wave 64x64). Ring of 4 half-slots (A 32 KB + W 64 KB). Per wave per half:
// 3 gload_lds (1 A + 2 W). Steady wait vmcnt(6); tail 3 -> 0.
__global__ __launch_bounds__(512, 2) void gemm2_v6(
    const bf16_t* __restrict__ pq, const bf16_t* __restrict__ Wpb,
    const bf16_t* __restrict__ Wqb, const float* __restrict__ bp,
    const float* __restrict__ bq, float* __restrict__ out) {
  __shared__ bf16_t lA[4][128 * 32];  // 32 KB
  __shared__ bf16_t lW[4][256 * 32];  // 64 KB
  const int tid = threadIdx.x, lane = tid & 63, wv = tid >> 6;
  const int bid = blockIdx.x;
  const int t = (bid & 7) * 32 + (bid >> 3);  // XCD swizzle, 256 blocks
  const int z = t >> 7;
  const int s = t & 127;
  const int row0 = (s & 7) * 128, col0 = (s >> 3) * 256;

  const bf16_t* A = pq + (size_t)z * SZ;
  const bf16_t* Wm = z ? Wqb : Wpb;
  const float* bias = z ? bq : bp;
  float* C = out + (size_t)z * SZ;

  const int wm = (wv >> 2) * 64, wn = (wv & 3) * 64;
  const int lr = lane & 15, kq = lane >> 4;
  const int kswz = (kq ^ ((lr >> 1) & 3)) << 3;

  const int srow = lane >> 2;
  const int sc = (lane & 3) ^ ((lane >> 3) & 3);
  const bf16_t* gA0 = A + (size_t)(row0 + wv * 16 + srow) * NB + sc * 8;
  const bf16_t* gW0 = Wm + (size_t)(col0 + wv * 32 + srow) * NB + sc * 8;
  const bf16_t* gW1 = gW0 + (size_t)16 * NB;

#define G2_ISS(sl, ko)                                                         \
  do {                                                                         \
    GLOAD16(gA0 + (ko), &lA[sl][wv * 512]);                                    \
    GLOAD16(gW0 + (ko), &lW[sl][wv * 1024]);                                   \
    GLOAD16(gW1 + (ko), &lW[sl][wv * 1024 + 512]);                             \
  } while (0)

  int aoff[4], woff[4];
#pragma unroll
  for (int m = 0; m < 4; ++m) aoff[m] = (wm + m * 16 + lr) * 32 + kswz;
#pragma unroll
  for (int n = 0; n < 4; ++n) woff[n] = (wn + n * 16 + lr) * 32 + kswz;

  f32x4 acc[4][4] = {};

#pragma unroll
  for (int hh = 0; hh < 3; ++hh) G2_ISS(hh, hh * 32);
  asm volatile("s_waitcnt vmcnt(6)" ::: "memory");
  SBAR();
  SCHEDB();

  const int HTOT = 2 * (NB / 64);
  for (int h = 0; h < HTOT; ++h) {
    const int slot = h & 3;
    const bool pf = (h + 3) < HTOT;
    const int pslot = (h + 3) & 3;
    const int pko = (h + 3) * 32;

    bf16x8 av[4], bw[4];
#pragma unroll
    for (int m = 0; m < 4; ++m)
      av[m] = *reinterpret_cast<const bf16x8*>(&lA[slot][aoff[m]]);
#pragma unroll
    for (int n = 0; n < 4; ++n)
      bw[n] = *reinterpret_cast<const bf16x8*>(&lW[slot][woff[n]]);
    if (pf) G2_ISS(pslot, pko);
    SBAR();
    SCHEDB();
    __builtin_amdgcn_s_setprio(1);
#pragma unroll
    for (int m = 0; m < 4; ++m)
#pragma unroll
      for (int n = 0; n < 4; ++n)
        acc[m][n] = MFMA16(av[m], bw[n], acc[m][n]);
    __builtin_amdgcn_s_setprio(0);
    SCHEDB();
    if (h < HTOT - 3)
      asm volatile("s_waitcnt vmcnt(6)" ::: "memory");
    else if (h == HTOT - 3)
      asm volatile("s_waitcnt vmcnt(3)" ::: "memory");
    else if (h == HTOT - 2)
      asm volatile("s_waitcnt vmcnt(0)" ::: "memory");
    SBAR();
    SCHEDB();
  }

  const int fr = lane & 15, fq = kq;
#pragma unroll
  for (int m = 0; m < 4; ++m)
#pragma unroll
    for (int n = 0; n < 4; ++n)
#pragma unroll
      for (int j = 0; j < 4; ++j) {
        int r = row0 + wm + m * 16 + fq * 4 + j;
        int c = col0 + wn + n * 16 + fr;
        C[(size_t)r * NB + c] = acc[m][n][j] + bias[c];
      }
}

// ---------------- fallbacks (compile-only safety net) ----------------
__device__ __forceinline__ int swz_off32(int r, int kk) {
  return r * 32 + ((kk ^ ((r >> 1) & 3)) << 3);
}

__device__ __forceinline__ void fb_stage_f32(const float* __restrict__ src,
                                             int row0, int k0, bf16_t* lds, int t) {
  int r = t >> 2, kk = t & 3;
  const float* p = src + (size_t)(row0 + r) * NB + k0 + (kk << 3);
  float4 v0 = *reinterpret_cast<const float4*>(p);
  float4 v1 = *reinterpret_cast<const float4*>(p + 4);
  *reinterpret_cast<bf16x8*>(lds + swz_off32(r, kk)) = cvt8(v0, v1);
}

__global__ __launch_bounds__(256, 2) void fb_gemm2(
    const bf16_t* __restrict__ pq, const float* __restrict__ Wp,
    const float* __restrict__ Wq, const float* __restrict__ bp,
    const float* __restrict__ bq, float* __restrict__ out) {
  __shared__ bf16_t lA[128 * 32], lW[128 * 32];
  const int z = blockIdx.z;
  const bf16_t* A = pq + (size_t)z * SZ;
  const float* Wm = z ? Wq : Wp;
  const float* bias = z ? bq : bp;
  float* C = out + (size_t)z * SZ;
  const int tid = threadIdx.x;
  const int lane = tid & 63, wv = tid >> 6;
  const int wm = (wv >> 1) * 64, wn = (wv & 1) * 64;
  const int row0 = blockIdx.y * 128, col0 = blockIdx.x * 128;
  const int lr = lane & 15, kq = lane >> 4;
  const int fslot = (kq ^ ((lr >> 1) & 3)) << 3;
  f32x4 acc[4][4] = {};
  for (int kt = 0; kt < NB; kt += 32) {
#pragma unroll
    for (int p = 0; p < 2; ++p) {
      int cb = p * 256 + wv * 64;
      int ci = cb + lane;
      int r = ci >> 2, kl = ci & 3;
      int ks = kl ^ ((r >> 1) & 3);
      const bf16_t* g = A + (size_t)(row0 + r) * NB + kt + (ks << 3);
      GLOAD16(g, lA + cb * 8);
    }
#pragma unroll
    for (int p = 0; p < 2; ++p)
      fb_stage_f32(Wm, col0, kt, lW, p * 256 + tid);
    __syncthreads();
    bf16x8 af[4], bg[4];
#pragma unroll
    for (int m = 0; m < 4; ++m)
      af[m] = *reinterpret_cast<const bf16x8*>(lA + (wm + m * 16 + lr) * 32 + fslot);
#pragma unroll
    for (int n = 0; n < 4; ++n)
      bg[n] = *reinterpret_cast<const bf16x8*>(lW + (wn + n * 16 + lr) * 32 + fslot);
#pragma unroll
    for (int m = 0; m < 4; ++m)
#pragma unroll
      for (int n = 0; n < 4; ++n)
        acc[m][n] = MFMA16(af[m], bg[n], acc[m][n]);
    __syncthreads();
  }
  const int fr = lane & 15, fq = lane >> 4;
#pragma unroll
  for (int m = 0; m < 4; ++m)
#pragma unroll
    for (int n = 0; n < 4; ++n)
#pragma unroll
      for (int j = 0; j < 4; ++j) {
        int r = row0 + wm + m * 16 + fq * 4 + j;
        int c = col0 + wn + n * 16 + fr;
        C[(size_t)r * NB + c] = acc[m][n][j] + bias[c];
      }
}

__global__ __launch_bounds__(512, 2) void fb_fused1(
    const float* __restrict__ u, const float* __restrict__ w,
    const float* __restrict__ G, const float* __restrict__ Bm,
    const float* __restrict__ bias_p, const float* __restrict__ bias_q,
    bf16_t* __restrict__ pq) {
  __shared__ bf16_t lU[128 * 32], lW[128 * 32], lG[128 * 32], lB[128 * 32];
  const int tid = threadIdx.x;
  const int lane = tid & 63, wv = tid >> 6;
  const int wm = (wv >> 2) * 64, wn = (wv & 3) * 32;
  const int row0 = blockIdx.y * 128, col0 = blockIdx.x * 128;
  const int lr = lane & 15, kq = lane >> 4;
  const int fslot = (kq ^ ((lr >> 1) & 3)) << 3;
  f32x4 aS[4][2] = {}, aT[4][2] = {};
  for (int kt = 0; kt < NB; kt += 32) {
    fb_stage_f32(u, row0, kt, lU, tid);
    fb_stage_f32(w, row0, kt, lW, tid);
    fb_stage_f32(G, col0, kt, lG, tid);
    fb_stage_f32(Bm, col0, kt, lB, tid);
    __syncthreads();
    bf16x8 au[4], aw[4], bG[2], bB[2], bBn[2];
#pragma unroll
    for (int m = 0; m < 4; ++m) {
      int off = (wm + m * 16 + lr) * 32 + fslot;
      au[m] = *reinterpret_cast<const bf16x8*>(lU + off);
      aw[m] = *reinterpret_cast<const bf16x8*>(lW + off);
    }
#pragma unroll
    for (int n = 0; n < 2; ++n) {
      int off = (wn + n * 16 + lr) * 32 + fslot;
      bG[n] = *reinterpret_cast<const bf16x8*>(lG + off);
      bB[n] = *reinterpret_cast<const bf16x8*>(lB + off);
      bBn[n] = neg8(bB[n]);
    }
#pragma unroll
    for (int m = 0; m < 4; ++m)
#pragma unroll
      for (int n = 0; n < 2; ++n) {
        aS[m][n] = MFMA16(au[m], bG[n], aS[m][n]);
        aS[m][n] = MFMA16(aw[m], bBn[n], aS[m][n]);
        aT[m][n] = MFMA16(aw[m], bG[n], aT[m][n]);
        aT[m][n] = MFMA16(au[m], bB[n], aT[m][n]);
      }
    __syncthreads();
  }
  const int fr = lane & 15, fq = lane >> 4;
#pragma unroll
  for (int m = 0; m < 4; ++m)
#pragma unroll
    for (int n = 0; n < 2; ++n)
#pragma unroll
      for (int j = 0; j < 4; ++j) {
        int r = row0 + wm + m * 16 + fq * 4 + j;
        int c = col0 + wn + n * 16 + fr;
        size_t idx = (size_t)r * NB + c;
        float U = u[idx], W = w[idx];
        float S = aS[m][n][j], T = aT[m][n][j];
        pq[idx] = (bf16_t)(U * S + W * T + bias_p[c]);
        pq[SZ + idx] = (bf16_t)(W * S - U * T + bias_q[c]);
      }
}

extern "C" void kernel_launch(void* const* d_in, const int* in_sizes, int n_in,
                              void* d_out, int out_size, void* d_ws, size_t ws_size,
                              hipStream_t stream) {
  const float* u = (const float*)d_in[0];
  const float* w = (const float*)d_in[1];
  const float* G = (const float*)d_in[2];
  const float* Bm = (const float*)d_in[3];
  const float* bias_p = (const float*)d_in[4];
  const float* bias_q = (const float*)d_in[5];
  const float* Wp = (const float*)d_in[6];
  const float* bp = (const float*)d_in[7];
  const float* Wq = (const float*)d_in[8];
  const float* bq = (const float*)d_in[9];
  (void)in_sizes; (void)n_in; (void)out_size;

  const size_t need_full = (6 * SZ + 4 * NN) * sizeof(bf16_t);  // 176 MB
  const size_t need_mid = (6 * SZ + 2 * NN) * sizeof(bf16_t);   // 112 MB

  if (ws_size >= need_full) {
    bf16_t* ws = (bf16_t*)d_ws;
    bf16_t* ubf = ws;
    bf16_t* wbf = ws + SZ;
    bf16_t* Gbf = ws + 2 * SZ;
    bf16_t* Bbf = Gbf + NN;
    bf16_t* Wpb = Bbf + NN;
    bf16_t* Wqb = Wpb + NN;
    bf16_t* pqw = Wqb + NN;
    prep6_kernel<<<2048, 256, 0, stream>>>(u, w, G, Bm, Wp, Wq, ws);
    fused1_v5<<<256, 512, 0, stream>>>(u, w, ubf, wbf, Gbf, Bbf,
                                       bias_p, bias_q, pqw);
    gemm2_v6<<<256, 512, 0, stream>>>(pqw, Wpb, Wqb, bp, bq, (float*)d_out);
  } else if (ws_size >= need_mid) {
    bf16_t* ws = (bf16_t*)d_ws;
    bf16_t* ubf = ws;
    bf16_t* wbf = ws + SZ;
    bf16_t* Gbf = ws + 2 * SZ;
    bf16_t* Bbf = Gbf + NN;
    bf16_t* pqw = Bbf + NN;
    prep4_kernel<<<2048, 256, 0, stream>>>(u, w, G, Bm, ws);
    fused1_v5<<<256, 512, 0, stream>>>(u, w, ubf, wbf, Gbf, Bbf,
                                       bias_p, bias_q, pqw);
    fb_gemm2<<<dim3(NB / 128, MB / 128, 2), 256, 0, stream>>>(
        pqw, Wp, Wq, bp, bq, (float*)d_out);
  } else {
    bf16_t* pqw = (bf16_t*)d_ws;
    fb_fused1<<<dim3(NB / 128, MB / 128), 512, 0, stream>>>(
        u, w, G, Bm, bias_p, bias_q, pqw);
    fb_gemm2<<<dim3(NB / 128, MB / 128, 2), 256, 0, stream>>>(
        pqw, Wp, Wq, bp, bq, (float*)d_out);
  }
}

// Round 8
// 306.257 us; speedup vs baseline: 1.5972x; 1.0385x over previous
//
#include <hip/hip_runtime.h>
#include <hip/hip_bf16.h>

#define NB 4096
#define MB 1024
#define SZ ((size_t)MB * NB)
#define NN ((size_t)NB * NB)

typedef __bf16 bf16_t;
typedef __attribute__((ext_vector_type(8))) __bf16 bf16x8;
typedef __attribute__((ext_vector_type(4))) float f32x4;
typedef __attribute__((ext_vector_type(4))) unsigned int u32x4;

#define AS1 __attribute__((address_space(1)))
#define AS3 __attribute__((address_space(3)))
#define GLOAD16(gp, lp)                                                        \
  __builtin_amdgcn_global_load_lds((const AS1 unsigned int*)(gp),              \
                                   (AS3 unsigned int*)(lp), 16, 0, 0)
#define SBAR() __builtin_amdgcn_s_barrier()
#define SCHEDB() __builtin_amdgcn_sched_barrier(0)
#define MFMA16(a, b, c) __builtin_amdgcn_mfma_f32_16x16x32_bf16((a), (b), (c), 0, 0, 0)

// Half-K-tile LDS layout: [rows][32 k] bf16, 4 cells of 8 bf16 (16B) per row.
// cell (r, c) stored at slot s = c ^ ((r>>1)&3) (bank-uniform for b128 reads;
// verified 0 conflicts r7). gload_lds writes linearly (lane l -> row
// base+(l>>2), slot l&3); global source pre-swizzled: chunk c = (l&3)^((l>>3)&3).
// Read of k-chunk kq at row 16a+lr: slot kq^((lr>>1)&3).
//
// Sync design (r8): ONE {counted vmcnt; s_barrier} per K-half. Ring-of-4
// slots; at half h waves read slot h&3 and issue prefetch into (h+3)&3 —
// distinct mod 4, and the end-of-half barrier bounds wave skew to one half,
// so no mid-half barriers are needed. ds_read/MFMA/gload_lds of a half are
// left to the compiler to interleave (fine-grained lgkmcnt) so the LDS unit
// and the matrix pipes run concurrently instead of in barrier-locked phases.

__device__ __forceinline__ bf16x8 neg8(bf16x8 x) {
  u32x4 t;
  __builtin_memcpy(&t, &x, 16);
  t ^= 0x80008000u;
  bf16x8 y;
  __builtin_memcpy(&y, &t, 16);
  return y;
}

__device__ __forceinline__ bf16x8 cvt8(float4 a, float4 b) {
  bf16x8 v;
  v[0] = (bf16_t)a.x; v[1] = (bf16_t)a.y; v[2] = (bf16_t)a.z; v[3] = (bf16_t)a.w;
  v[4] = (bf16_t)b.x; v[5] = (bf16_t)b.y; v[6] = (bf16_t)b.z; v[7] = (bf16_t)b.w;
  return v;
}

// ---------------- prep: f32 -> bf16 ----------------
#define ITEM_S (SZ / 8)
#define ITEM_N (NN / 8)

__global__ __launch_bounds__(256) void prep6_kernel(
    const float* __restrict__ u, const float* __restrict__ w,
    const float* __restrict__ G, const float* __restrict__ Bm,
    const float* __restrict__ Wp, const float* __restrict__ Wq,
    bf16_t* __restrict__ ws) {
  size_t stride = (size_t)gridDim.x * blockDim.x;
  const size_t tot = 2 * ITEM_S + 4 * ITEM_N;
  for (size_t i = (size_t)blockIdx.x * blockDim.x + threadIdx.x; i < tot;
       i += stride) {
    const float* src;
    bf16_t* dst;
    size_t off;
    if (i < ITEM_S) { src = u; dst = ws; off = i; }
    else if (i < 2 * ITEM_S) { src = w; dst = ws + SZ; off = i - ITEM_S; }
    else if (i < 2 * ITEM_S + ITEM_N) { src = G; dst = ws + 2 * SZ; off = i - 2 * ITEM_S; }
    else if (i < 2 * ITEM_S + 2 * ITEM_N) { src = Bm; dst = ws + 2 * SZ + NN; off = i - 2 * ITEM_S - ITEM_N; }
    else if (i < 2 * ITEM_S + 3 * ITEM_N) { src = Wp; dst = ws + 2 * SZ + 2 * NN; off = i - 2 * ITEM_S - 2 * ITEM_N; }
    else { src = Wq; dst = ws + 2 * SZ + 3 * NN; off = i - 2 * ITEM_S - 3 * ITEM_N; }
    const float4* s = reinterpret_cast<const float4*>(src) + off * 2;
    reinterpret_cast<bf16x8*>(dst)[off] = cvt8(s[0], s[1]);
  }
}

__global__ __launch_bounds__(256) void prep4_kernel(
    const float* __restrict__ u, const float* __restrict__ w,
    const float* __restrict__ G, const float* __restrict__ Bm,
    bf16_t* __restrict__ ws) {
  size_t stride = (size_t)gridDim.x * blockDim.x;
  const size_t tot = 2 * ITEM_S + 2 * ITEM_N;
  for (size_t i = (size_t)blockIdx.x * blockDim.x + threadIdx.x; i < tot;
       i += stride) {
    const float* src;
    bf16_t* dst;
    size_t off;
    if (i < ITEM_S) { src = u; dst = ws; off = i; }
    else if (i < 2 * ITEM_S) { src = w; dst = ws + SZ; off = i - ITEM_S; }
    else if (i < 2 * ITEM_S + ITEM_N) { src = G; dst = ws + 2 * SZ; off = i - 2 * ITEM_S; }
    else { src = Bm; dst = ws + 2 * SZ + NN; off = i - 2 * ITEM_S - ITEM_N; }
    const float4* s = reinterpret_cast<const float4*>(src) + off * 2;
    reinterpret_cast<bf16x8*>(dst)[off] = cvt8(s[0], s[1]);
  }
}

// ---------------- fused stage 1: flat half, counted-vmcnt ring ------------
// S = u@G^T - w@B^T, T = w@G^T + u@B^T; p_mid/q_mid epilogue.
// Tile 128x128, 8 waves (2m x 4n, wave 64x32). Ring of 4 half-slots (128 KB).
// Per wave per half: 12 ds_read_b128 + 4 gload_lds + 32 MFMA, one sync.
__global__ __launch_bounds__(512, 2) void fused1_v6(
    const float* __restrict__ u, const float* __restrict__ w,
    const bf16_t* __restrict__ ubf, const bf16_t* __restrict__ wbf,
    const bf16_t* __restrict__ Gbf, const bf16_t* __restrict__ Bbf,
    const float* __restrict__ bias_p, const float* __restrict__ bias_q,
    bf16_t* __restrict__ pq) {
  __shared__ bf16_t lds[4][4][128 * 32];  // [slot][op][row*32] = 128 KB
  const int tid = threadIdx.x, lane = tid & 63, wv = tid >> 6;
  const int bid = blockIdx.x;
  const int t = (bid & 7) * 32 + (bid >> 3);  // XCD swizzle, 256 blocks
  const int row0 = (t & 7) * 128, col0 = (t >> 3) * 128;
  const int wm = (wv >> 2) * 64, wn = (wv & 3) * 32;
  const int lr = lane & 15, kq = lane >> 4;
  const int kswz = (kq ^ ((lr >> 1) & 3)) << 3;

  const int srow = wv * 16 + (lane >> 2);
  const int sc = (lane & 3) ^ ((lane >> 3) & 3);
  const bf16_t* gsrc[4];
  gsrc[0] = ubf + (size_t)(row0 + srow) * NB + sc * 8;
  gsrc[1] = wbf + (size_t)(row0 + srow) * NB + sc * 8;
  gsrc[2] = Gbf + (size_t)(col0 + srow) * NB + sc * 8;
  gsrc[3] = Bbf + (size_t)(col0 + srow) * NB + sc * 8;

#define F1_ISS(op, sl, ko) GLOAD16(gsrc[op] + (ko), &lds[sl][op][wv * 512])

  int aoff[4], boff[2];
#pragma unroll
  for (int m = 0; m < 4; ++m) aoff[m] = (wm + m * 16 + lr) * 32 + kswz;
#pragma unroll
  for (int n = 0; n < 2; ++n) boff[n] = (wn + n * 16 + lr) * 32 + kswz;

  f32x4 aS[4][2] = {}, aT[4][2] = {};

  // prologue: issue halves 0,1,2
#pragma unroll
  for (int hh = 0; hh < 3; ++hh) {
    F1_ISS(0, hh, hh * 32);
    F1_ISS(1, hh, hh * 32);
    F1_ISS(2, hh, hh * 32);
    F1_ISS(3, hh, hh * 32);
  }
  asm volatile("s_waitcnt vmcnt(8)" ::: "memory");  // half 0 landed
  SBAR();
  SCHEDB();

  const int HTOT = 2 * (NB / 64);  // 128 halves
  for (int h = 0; h < HTOT; ++h) {
    const int slot = h & 3;
    const bool pf = (h + 3) < HTOT;
    const int pslot = (h + 3) & 3;
    const int pko = (h + 3) * 32;

    bf16x8 bG[2], bB[2], au[4], aw[4];
#pragma unroll
    for (int n = 0; n < 2; ++n) {
      bG[n] = *reinterpret_cast<const bf16x8*>(&lds[slot][2][boff[n]]);
      bB[n] = *reinterpret_cast<const bf16x8*>(&lds[slot][3][boff[n]]);
    }
#pragma unroll
    for (int m = 0; m < 4; ++m) {
      au[m] = *reinterpret_cast<const bf16x8*>(&lds[slot][0][aoff[m]]);
      aw[m] = *reinterpret_cast<const bf16x8*>(&lds[slot][1][aoff[m]]);
    }
    if (pf) {
      F1_ISS(0, pslot, pko);
      F1_ISS(1, pslot, pko);
      F1_ISS(2, pslot, pko);
      F1_ISS(3, pslot, pko);
    }
    bf16x8 bBn[2] = {neg8(bB[0]), neg8(bB[1])};
#pragma unroll
    for (int m = 0; m < 4; ++m)
#pragma unroll
      for (int n = 0; n < 2; ++n) {
        aS[m][n] = MFMA16(au[m], bG[n], aS[m][n]);
        aS[m][n] = MFMA16(aw[m], bBn[n], aS[m][n]);
        aT[m][n] = MFMA16(aw[m], bG[n], aT[m][n]);
        aT[m][n] = MFMA16(au[m], bB[n], aT[m][n]);
      }
    // one counted sync per half: next slot's data landed on every wave
    if (h < HTOT - 3)
      asm volatile("s_waitcnt vmcnt(8)" ::: "memory");
    else if (h == HTOT - 3)
      asm volatile("s_waitcnt vmcnt(4)" ::: "memory");
    else if (h == HTOT - 2)
      asm volatile("s_waitcnt vmcnt(0)" ::: "memory");
    SBAR();
    SCHEDB();
  }

  // epilogue: combine with u,w (f32) + biases -> p_mid/q_mid bf16
  const int fr = lane & 15, fq = kq;
#pragma unroll
  for (int m = 0; m < 4; ++m)
#pragma unroll
    for (int n = 0; n < 2; ++n)
#pragma unroll
      for (int j = 0; j < 4; ++j) {
        int r = row0 + wm + m * 16 + fq * 4 + j;
        int c = col0 + wn + n * 16 + fr;
        size_t idx = (size_t)r * NB + c;
        float U = u[idx], W = w[idx];
        float S = aS[m][n][j], T = aT[m][n][j];
        pq[idx] = (bf16_t)(U * S + W * T + bias_p[c]);
        pq[SZ + idx] = (bf16_t)(W * S - U * T + bias_q[c]);
      }
}

// ---------------- stage 2: flat half, counted-vmcnt ring ----------------
// out_z = pq_z @ W_z^T + b_z (f32). Tile 128(M)x256(N), 8 waves (2m x 4n,
// wave 64x64). Ring of 4 half-slots (96 KB). Per wave per half: 8 ds_read +
// 3 gload_lds + 16 MFMA, one sync.
__global__ __launch_bounds__(512, 2) void gemm2_v7(
    const bf16_t* __restrict__ pq, const bf16_t* __restrict__ Wpb,
    const bf16_t* __restrict__ Wqb, const float* __restrict__ bp,
    const float* __restrict__ bq, float* __restrict__ out) {
  __shared__ bf16_t lA[4][128 * 32];  // 32 KB
  __shared__ bf16_t lW[4][256 * 32];  // 64 KB
  const int tid = threadIdx.x, lane = tid & 63, wv = tid >> 6;
  const int bid = blockIdx.x;
  const int t = (bid & 7) * 32 + (bid >> 3);  // XCD swizzle, 256 blocks
  const int z = t >> 7;
  const int s = t & 127;
  const int row0 = (s & 7) * 128, col0 = (s >> 3) * 256;

  const bf16_t* A = pq + (size_t)z * SZ;
  const bf16_t* Wm = z ? Wqb : Wpb;
  const float* bias = z ? bq : bp;
  float* C = out + (size_t)z * SZ;

  const int wm = (wv >> 2) * 64, wn = (wv & 3) * 64;
  const int lr = lane & 15, kq = lane >> 4;
  const int kswz = (kq ^ ((lr >> 1) & 3)) << 3;

  const int srow = lane >> 2;
  const int sc = (lane & 3) ^ ((lane >> 3) & 3);
  const bf16_t* gA0 = A + (size_t)(row0 + wv * 16 + srow) * NB + sc * 8;
  const bf16_t* gW0 = Wm + (size_t)(col0 + wv * 32 + srow) * NB + sc * 8;
  const bf16_t* gW1 = gW0 + (size_t)16 * NB;

#define G2_ISS(sl, ko)                                                         \
  do {                                                                         \
    GLOAD16(gA0 + (ko), &lA[sl][wv * 512]);                                    \
    GLOAD16(gW0 + (ko), &lW[sl][wv * 1024]);                                   \
    GLOAD16(gW1 + (ko), &lW[sl][wv * 1024 + 512]);                             \
  } while (0)

  int aoff[4], woff[4];
#pragma unroll
  for (int m = 0; m < 4; ++m) aoff[m] = (wm + m * 16 + lr) * 32 + kswz;
#pragma unroll
  for (int n = 0; n < 4; ++n) woff[n] = (wn + n * 16 + lr) * 32 + kswz;

  f32x4 acc[4][4] = {};

#pragma unroll
  for (int hh = 0; hh < 3; ++hh) G2_ISS(hh, hh * 32);
  asm volatile("s_waitcnt vmcnt(6)" ::: "memory");
  SBAR();
  SCHEDB();

  const int HTOT = 2 * (NB / 64);
  for (int h = 0; h < HTOT; ++h) {
    const int slot = h & 3;
    const bool pf = (h + 3) < HTOT;
    const int pslot = (h + 3) & 3;
    const int pko = (h + 3) * 32;

    bf16x8 av[4], bw[4];
#pragma unroll
    for (int m = 0; m < 4; ++m)
      av[m] = *reinterpret_cast<const bf16x8*>(&lA[slot][aoff[m]]);
#pragma unroll
    for (int n = 0; n < 4; ++n)
      bw[n] = *reinterpret_cast<const bf16x8*>(&lW[slot][woff[n]]);
    if (pf) G2_ISS(pslot, pko);
#pragma unroll
    for (int m = 0; m < 4; ++m)
#pragma unroll
      for (int n = 0; n < 4; ++n)
        acc[m][n] = MFMA16(av[m], bw[n], acc[m][n]);
    if (h < HTOT - 3)
      asm volatile("s_waitcnt vmcnt(6)" ::: "memory");
    else if (h == HTOT - 3)
      asm volatile("s_waitcnt vmcnt(3)" ::: "memory");
    else if (h == HTOT - 2)
      asm volatile("s_waitcnt vmcnt(0)" ::: "memory");
    SBAR();
    SCHEDB();
  }

  const int fr = lane & 15, fq = kq;
#pragma unroll
  for (int m = 0; m < 4; ++m)
#pragma unroll
    for (int n = 0; n < 4; ++n)
#pragma unroll
      for (int j = 0; j < 4; ++j) {
        int r = row0 + wm + m * 16 + fq * 4 + j;
        int c = col0 + wn + n * 16 + fr;
        C[(size_t)r * NB + c] = acc[m][n][j] + bias[c];
      }
}

// ---------------- fallbacks (compile-only safety net) ----------------
__device__ __forceinline__ int swz_off32(int r, int kk) {
  return r * 32 + ((kk ^ ((r >> 1) & 3)) << 3);
}

__device__ __forceinline__ void fb_stage_f32(const float* __restrict__ src,
                                             int row0, int k0, bf16_t* lds, int t) {
  int r = t >> 2, kk = t & 3;
  const float* p = src + (size_t)(row0 + r) * NB + k0 + (kk << 3);
  float4 v0 = *reinterpret_cast<const float4*>(p);
  float4 v1 = *reinterpret_cast<const float4*>(p + 4);
  *reinterpret_cast<bf16x8*>(lds + swz_off32(r, kk)) = cvt8(v0, v1);
}

__global__ __launch_bounds__(256, 2) void fb_gemm2(
    const bf16_t* __restrict__ pq, const float* __restrict__ Wp,
    const float* __restrict__ Wq, const float* __restrict__ bp,
    const float* __restrict__ bq, float* __restrict__ out) {
  __shared__ bf16_t lA[128 * 32], lW[128 * 32];
  const int z = blockIdx.z;
  const bf16_t* A = pq + (size_t)z * SZ;
  const float* Wm = z ? Wq : Wp;
  const float* bias = z ? bq : bp;
  float* C = out + (size_t)z * SZ;
  const int tid = threadIdx.x;
  const int lane = tid & 63, wv = tid >> 6;
  const int wm = (wv >> 1) * 64, wn = (wv & 1) * 64;
  const int row0 = blockIdx.y * 128, col0 = blockIdx.x * 128;
  const int lr = lane & 15, kq = lane >> 4;
  const int fslot = (kq ^ ((lr >> 1) & 3)) << 3;
  f32x4 acc[4][4] = {};
  for (int kt = 0; kt < NB; kt += 32) {
#pragma unroll
    for (int p = 0; p < 2; ++p) {
      int cb = p * 256 + wv * 64;
      int ci = cb + lane;
      int r = ci >> 2, kl = ci & 3;
      int ks = kl ^ ((r >> 1) & 3);
      const bf16_t* g = A + (size_t)(row0 + r) * NB + kt + (ks << 3);
      GLOAD16(g, lA + cb * 8);
    }
#pragma unroll
    for (int p = 0; p < 2; ++p)
      fb_stage_f32(Wm, col0, kt, lW, p * 256 + tid);
    __syncthreads();
    bf16x8 af[4], bg[4];
#pragma unroll
    for (int m = 0; m < 4; ++m)
      af[m] = *reinterpret_cast<const bf16x8*>(lA + (wm + m * 16 + lr) * 32 + fslot);
#pragma unroll
    for (int n = 0; n < 4; ++n)
      bg[n] = *reinterpret_cast<const bf16x8*>(lW + (wn + n * 16 + lr) * 32 + fslot);
#pragma unroll
    for (int m = 0; m < 4; ++m)
#pragma unroll
      for (int n = 0; n < 4; ++n)
        acc[m][n] = MFMA16(af[m], bg[n], acc[m][n]);
    __syncthreads();
  }
  const int fr = lane & 15, fq = lane >> 4;
#pragma unroll
  for (int m = 0; m < 4; ++m)
#pragma unroll
    for (int n = 0; n < 4; ++n)
#pragma unroll
      for (int j = 0; j < 4; ++j) {
        int r = row0 + wm + m * 16 + fq * 4 + j;
        int c = col0 + wn + n * 16 + fr;
        C[(size_t)r * NB + c] = acc[m][n][j] + bias[c];
      }
}

__global__ __launch_bounds__(512, 2) void fb_fused1(
    const float* __restrict__ u, const float* __restrict__ w,
    const float* __restrict__ G, const float* __restrict__ Bm,
    const float* __restrict__ bias_p, const float* __restrict__ bias_q,
    bf16_t* __restrict__ pq) {
  __shared__ bf16_t lU[128 * 32], lW[128 * 32], lG[128 * 32], lB[128 * 32];
  const int tid = threadIdx.x;
  const int lane = tid & 63, wv = tid >> 6;
  const int wm = (wv >> 2) * 64, wn = (wv & 3) * 32;
  const int row0 = blockIdx.y * 128, col0 = blockIdx.x * 128;
  const int lr = lane & 15, kq = lane >> 4;
  const int fslot = (kq ^ ((lr >> 1) & 3)) << 3;
  f32x4 aS[4][2] = {}, aT[4][2] = {};
  for (int kt = 0; kt < NB; kt += 32) {
    fb_stage_f32(u, row0, kt, lU, tid);
    fb_stage_f32(w, row0, kt, lW, tid);
    fb_stage_f32(G, col0, kt, lG, tid);
    fb_stage_f32(Bm, col0, kt, lB, tid);
    __syncthreads();
    bf16x8 au[4], aw[4], bG[2], bB[2], bBn[2];
#pragma unroll
    for (int m = 0; m < 4; ++m) {
      int off = (wm + m * 16 + lr) * 32 + fslot;
      au[m] = *reinterpret_cast<const bf16x8*>(lU + off);
      aw[m] = *reinterpret_cast<const bf16x8*>(lW + off);
    }
#pragma unroll
    for (int n = 0; n < 2; ++n) {
      int off = (wn + n * 16 + lr) * 32 + fslot;
      bG[n] = *reinterpret_cast<const bf16x8*>(lG + off);
      bB[n] = *reinterpret_cast<const bf16x8*>(lB + off);
      bBn[n] = neg8(bB[n]);
    }
#pragma unroll
    for (int m = 0; m < 4; ++m)
#pragma unroll
      for (int n = 0; n < 2; ++n) {
        aS[m][n] = MFMA16(au[m], bG[n], aS[m][n]);
        aS[m][n] = MFMA16(aw[m], bBn[n], aS[m][n]);
        aT[m][n] = MFMA16(aw[m], bG[n], aT[m][n]);
        aT[m][n] = MFMA16(au[m], bB[n], aT[m][n]);
      }
    __syncthreads();
  }
  const int fr = lane & 15, fq = lane >> 4;
#pragma unroll
  for (int m = 0; m < 4; ++m)
#pragma unroll
    for (int n = 0; n < 2; ++n)
#pragma unroll
      for (int j = 0; j < 4; ++j) {
        int r = row0 + wm + m * 16 + fq * 4 + j;
        int c = col0 + wn + n * 16 + fr;
        size_t idx = (size_t)r * NB + c;
        float U = u[idx], W = w[idx];
        float S = aS[m][n][j], T = aT[m][n][j];
        pq[idx] = (bf16_t)(U * S + W * T + bias_p[c]);
        pq[SZ + idx] = (bf16_t)(W * S - U * T + bias_q[c]);
      }
}

extern "C" void kernel_launch(void* const* d_in, const int* in_sizes, int n_in,
                              void* d_out, int out_size, void* d_ws, size_t ws_size,
                              hipStream_t stream) {
  const float* u = (const float*)d_in[0];
  const float* w = (const float*)d_in[1];
  const float* G = (const float*)d_in[2];
  const float* Bm = (const float*)d_in[3];
  const float* bias_p = (const float*)d_in[4];
  const float* bias_q = (const float*)d_in[5];
  const float* Wp = (const float*)d_in[6];
  const float* bp = (const float*)d_in[7];
  const float* Wq = (const float*)d_in[8];
  const float* bq = (const float*)d_in[9];
  (void)in_sizes; (void)n_in; (void)out_size;

  const size_t need_full = (6 * SZ + 4 * NN) * sizeof(bf16_t);  // 176 MB
  const size_t need_mid = (6 * SZ + 2 * NN) * sizeof(bf16_t);   // 112 MB

  if (ws_size >= need_full) {
    bf16_t* ws = (bf16_t*)d_ws;
    bf16_t* ubf = ws;
    bf16_t* wbf = ws + SZ;
    bf16_t* Gbf = ws + 2 * SZ;
    bf16_t* Bbf = Gbf + NN;
    bf16_t* Wpb = Bbf + NN;
    bf16_t* Wqb = Wpb + NN;
    bf16_t* pqw = Wqb + NN;
    prep6_kernel<<<2048, 256, 0, stream>>>(u, w, G, Bm, Wp, Wq, ws);
    fused1_v6<<<256, 512, 0, stream>>>(u, w, ubf, wbf, Gbf, Bbf,
                                       bias_p, bias_q, pqw);
    gemm2_v7<<<256, 512, 0, stream>>>(pqw, Wpb, Wqb, bp, bq, (float*)d_out);
  } else if (ws_size >= need_mid) {
    bf16_t* ws = (bf16_t*)d_ws;
    bf16_t* ubf = ws;
    bf16_t* wbf = ws + SZ;
    bf16_t* Gbf = ws + 2 * SZ;
    bf16_t* Bbf = Gbf + NN;
    bf16_t* pqw = Bbf + NN;
    prep4_kernel<<<2048, 256, 0, stream>>>(u, w, G, Bm, ws);
    fused1_v6<<<256, 512, 0, stream>>>(u, w, ubf, wbf, Gbf, Bbf,
                                       bias_p, bias_q, pqw);
    fb_gemm2<<<dim3(NB / 128, MB / 128, 2), 256, 0, stream>>>(
        pqw, Wp, Wq, bp, bq, (float*)d_out);
  } else {
    bf16_t* pqw = (bf16_t*)d_ws;
    fb_fused1<<<dim3(NB / 128, MB / 128), 512, 0, stream>>>(
        u, w, G, Bm, bias_p, bias_q, pqw);
    fb_gemm2<<<dim3(NB / 128, MB / 128, 2), 256, 0, stream>>>(
        pqw, Wp, Wq, bp, bq, (float*)d_out);
  }
}

// Round 9
// 300.537 us; speedup vs baseline: 1.6276x; 1.0190x over previous
//
#include <hip/hip_runtime.h>
#include <hip/hip_bf16.h>

#define NB 4096
#define MB 1024
#define SZ ((size_t)MB * NB)
#define NN ((size_t)NB * NB)

typedef __bf16 bf16_t;
typedef __attribute__((ext_vector_type(8))) __bf16 bf16x8;
typedef __attribute__((ext_vector_type(4))) float f32x4;
typedef __attribute__((ext_vector_type(4))) unsigned int u32x4;

#define AS1 __attribute__((address_space(1)))
#define AS3 __attribute__((address_space(3)))
#define GLOAD16(gp, lp)                                                        \
  __builtin_amdgcn_global_load_lds((const AS1 unsigned int*)(gp),              \
                                   (AS3 unsigned int*)(lp), 16, 0, 0)
#define SBAR() __builtin_amdgcn_s_barrier()
#define SCHEDB() __builtin_amdgcn_sched_barrier(0)
#define MFMA16(a, b, c) __builtin_amdgcn_mfma_f32_16x16x32_bf16((a), (b), (c), 0, 0, 0)
#define VMCNT4() asm volatile("s_waitcnt vmcnt(4)" ::: "memory")
#define VMCNT0() asm volatile("s_waitcnt vmcnt(0)" ::: "memory")

// Half-K-tile LDS layout (verified 0-conflict, r7): [rows][32 k] bf16, cells
// of 8 bf16; cell (r,c) at slot c ^ ((r>>1)&3). gload_lds writes linearly
// (lane l -> row base+(l>>2), slot l&3); global source chunk (l&3)^((l>>3)&3).
// Read of k-chunk kq at row 16a+lr: slot kq^((lr>>1)&3).
//
// Rotation pipeline (r9): ring-4 slots, prefetch distance 3, steady wait
// vmcnt(4) at end of half h => slot h+2 globally confirmed at the barrier.
// So during half h each wave ds_reads the frags of half h+1 (confirmed at
// the previous barrier) while MFMAs of half h run; after the barrier MFMAs
// start immediately from registers. Double frag set fA/fB (parity-unrolled).

__device__ __forceinline__ bf16x8 neg8(bf16x8 x) {
  u32x4 t;
  __builtin_memcpy(&t, &x, 16);
  t ^= 0x80008000u;
  bf16x8 y;
  __builtin_memcpy(&y, &t, 16);
  return y;
}

__device__ __forceinline__ bf16x8 cvt8(float4 a, float4 b) {
  bf16x8 v;
  v[0] = (bf16_t)a.x; v[1] = (bf16_t)a.y; v[2] = (bf16_t)a.z; v[3] = (bf16_t)a.w;
  v[4] = (bf16_t)b.x; v[5] = (bf16_t)b.y; v[6] = (bf16_t)b.z; v[7] = (bf16_t)b.w;
  return v;
}

// ---------------- prep: f32 -> bf16 ----------------
#define ITEM_S (SZ / 8)
#define ITEM_N (NN / 8)

__global__ __launch_bounds__(256) void prep6_kernel(
    const float* __restrict__ u, const float* __restrict__ w,
    const float* __restrict__ G, const float* __restrict__ Bm,
    const float* __restrict__ Wp, const float* __restrict__ Wq,
    bf16_t* __restrict__ ws) {
  size_t stride = (size_t)gridDim.x * blockDim.x;
  const size_t tot = 2 * ITEM_S + 4 * ITEM_N;
  for (size_t i = (size_t)blockIdx.x * blockDim.x + threadIdx.x; i < tot;
       i += stride) {
    const float* src;
    bf16_t* dst;
    size_t off;
    if (i < ITEM_S) { src = u; dst = ws; off = i; }
    else if (i < 2 * ITEM_S) { src = w; dst = ws + SZ; off = i - ITEM_S; }
    else if (i < 2 * ITEM_S + ITEM_N) { src = G; dst = ws + 2 * SZ; off = i - 2 * ITEM_S; }
    else if (i < 2 * ITEM_S + 2 * ITEM_N) { src = Bm; dst = ws + 2 * SZ + NN; off = i - 2 * ITEM_S - ITEM_N; }
    else if (i < 2 * ITEM_S + 3 * ITEM_N) { src = Wp; dst = ws + 2 * SZ + 2 * NN; off = i - 2 * ITEM_S - 2 * ITEM_N; }
    else { src = Wq; dst = ws + 2 * SZ + 3 * NN; off = i - 2 * ITEM_S - 3 * ITEM_N; }
    const float4* s = reinterpret_cast<const float4*>(src) + off * 2;
    reinterpret_cast<bf16x8*>(dst)[off] = cvt8(s[0], s[1]);
  }
}

__global__ __launch_bounds__(256) void prep4_kernel(
    const float* __restrict__ u, const float* __restrict__ w,
    const float* __restrict__ G, const float* __restrict__ Bm,
    bf16_t* __restrict__ ws) {
  size_t stride = (size_t)gridDim.x * blockDim.x;
  const size_t tot = 2 * ITEM_S + 2 * ITEM_N;
  for (size_t i = (size_t)blockIdx.x * blockDim.x + threadIdx.x; i < tot;
       i += stride) {
    const float* src;
    bf16_t* dst;
    size_t off;
    if (i < ITEM_S) { src = u; dst = ws; off = i; }
    else if (i < 2 * ITEM_S) { src = w; dst = ws + SZ; off = i - ITEM_S; }
    else if (i < 2 * ITEM_S + ITEM_N) { src = G; dst = ws + 2 * SZ; off = i - 2 * ITEM_S; }
    else { src = Bm; dst = ws + 2 * SZ + NN; off = i - 2 * ITEM_S - ITEM_N; }
    const float4* s = reinterpret_cast<const float4*>(src) + off * 2;
    reinterpret_cast<bf16x8*>(dst)[off] = cvt8(s[0], s[1]);
  }
}

struct F1Frag { bf16x8 au[4], aw[4], bG[2], bB[2]; };
struct G2Frag { bf16x8 av[4], bw[4]; };

// ---------------- fused stage 1: rotation pipeline ----------------
// S = u@G^T - w@B^T, T = w@G^T + u@B^T; p_mid/q_mid epilogue (bf16).
// Tile 128x128, 8 waves (2m x 4n, wave 64x32), ring-4 (128 KB).
// Per wave per half: 12 ds_read (next half) + 4 gload_lds + 32 MFMA, 1 sync.
__global__ __launch_bounds__(512, 2) void fused1_v7(
    const float* __restrict__ u, const float* __restrict__ w,
    const bf16_t* __restrict__ ubf, const bf16_t* __restrict__ wbf,
    const bf16_t* __restrict__ Gbf, const bf16_t* __restrict__ Bbf,
    const float* __restrict__ bias_p, const float* __restrict__ bias_q,
    bf16_t* __restrict__ pq) {
  __shared__ bf16_t lds[4][4][128 * 32];  // [slot][op][row*32] = 128 KB
  const int tid = threadIdx.x, lane = tid & 63, wv = tid >> 6;
  const int bid = blockIdx.x;
  const int t = (bid & 7) * 32 + (bid >> 3);  // XCD swizzle, 256 blocks
  const int row0 = (t & 7) * 128, col0 = (t >> 3) * 128;
  const int wm = (wv >> 2) * 64, wn = (wv & 3) * 32;
  const int lr = lane & 15, kq = lane >> 4;
  const int kswz = (kq ^ ((lr >> 1) & 3)) << 3;

  const int srow = wv * 16 + (lane >> 2);
  const int sc = (lane & 3) ^ ((lane >> 3) & 3);
  const bf16_t* gsrc[4];
  gsrc[0] = ubf + (size_t)(row0 + srow) * NB + sc * 8;
  gsrc[1] = wbf + (size_t)(row0 + srow) * NB + sc * 8;
  gsrc[2] = Gbf + (size_t)(col0 + srow) * NB + sc * 8;
  gsrc[3] = Bbf + (size_t)(col0 + srow) * NB + sc * 8;

#define F1_ISSUE(hh)                                                           \
  do {                                                                         \
    const int _sl = (hh) & 3;                                                  \
    const int _ko = (hh) * 32;                                                 \
    GLOAD16(gsrc[0] + _ko, &lds[_sl][0][wv * 512]);                            \
    GLOAD16(gsrc[1] + _ko, &lds[_sl][1][wv * 512]);                            \
    GLOAD16(gsrc[2] + _ko, &lds[_sl][2][wv * 512]);                            \
    GLOAD16(gsrc[3] + _ko, &lds[_sl][3][wv * 512]);                            \
  } while (0)

  int aoff[4], boff[2];
#pragma unroll
  for (int m = 0; m < 4; ++m) aoff[m] = (wm + m * 16 + lr) * 32 + kswz;
#pragma unroll
  for (int n = 0; n < 2; ++n) boff[n] = (wn + n * 16 + lr) * 32 + kswz;

#define F1_READ(F, sl)                                                         \
  do {                                                                         \
    const bf16_t* _b = &lds[sl][0][0];                                         \
    _Pragma("unroll") for (int _n = 0; _n < 2; ++_n) {                         \
      (F).bG[_n] = *reinterpret_cast<const bf16x8*>(_b + 2 * 4096 + boff[_n]); \
      (F).bB[_n] = *reinterpret_cast<const bf16x8*>(_b + 3 * 4096 + boff[_n]); \
    }                                                                          \
    _Pragma("unroll") for (int _m = 0; _m < 4; ++_m) {                         \
      (F).au[_m] = *reinterpret_cast<const bf16x8*>(_b + aoff[_m]);            \
      (F).aw[_m] = *reinterpret_cast<const bf16x8*>(_b + 4096 + aoff[_m]);     \
    }                                                                          \
  } while (0)

#define F1_MFMA(F)                                                             \
  do {                                                                         \
    bf16x8 _nB0 = neg8((F).bB[0]), _nB1 = neg8((F).bB[1]);                     \
    _Pragma("unroll") for (int _m = 0; _m < 4; ++_m) {                         \
      aS[_m][0] = MFMA16((F).au[_m], (F).bG[0], aS[_m][0]);                    \
      aS[_m][0] = MFMA16((F).aw[_m], _nB0, aS[_m][0]);                         \
      aT[_m][0] = MFMA16((F).aw[_m], (F).bG[0], aT[_m][0]);                    \
      aT[_m][0] = MFMA16((F).au[_m], (F).bB[0], aT[_m][0]);                    \
      aS[_m][1] = MFMA16((F).au[_m], (F).bG[1], aS[_m][1]);                    \
      aS[_m][1] = MFMA16((F).aw[_m], _nB1, aS[_m][1]);                         \
      aT[_m][1] = MFMA16((F).aw[_m], (F).bG[1], aT[_m][1]);                    \
      aT[_m][1] = MFMA16((F).au[_m], (F).bB[1], aT[_m][1]);                    \
    }                                                                          \
  } while (0)

#define F1_SYNC(hh)                                                            \
  do {                                                                         \
    if ((hh) <= 124) VMCNT4();                                                 \
    else if ((hh) == 125) VMCNT0();                                            \
    if ((hh) <= 125) SBAR();                                                   \
    SCHEDB();                                                                  \
  } while (0)

  f32x4 aS[4][2] = {}, aT[4][2] = {};
  F1Frag fA, fB;

  // prologue: issue halves 0,1,2; confirm 0,1; preload frags of half 0
  F1_ISSUE(0); F1_ISSUE(1); F1_ISSUE(2);
  VMCNT4();
  SBAR();
  SCHEDB();
  F1_READ(fA, 0);

  for (int h = 0; h < 127; h += 2) {
    // even half: compute fA, prefetch frags of h+1 into fB
    F1_READ(fB, (h + 1) & 3);
    if (h + 3 < 128) F1_ISSUE(h + 3);
    F1_MFMA(fA);
    F1_SYNC(h);
    // odd half
    const int h1 = h + 1;
    if (h1 < 127) {
      F1_READ(fA, (h1 + 1) & 3);
      if (h1 + 3 < 128) F1_ISSUE(h1 + 3);
      F1_MFMA(fB);
      F1_SYNC(h1);
    }
  }
  F1_MFMA(fB);  // half 127

  // epilogue: combine with u,w (f32) + biases -> p_mid/q_mid bf16
  const int fr = lane & 15, fq = kq;
#pragma unroll
  for (int m = 0; m < 4; ++m)
#pragma unroll
    for (int n = 0; n < 2; ++n)
#pragma unroll
      for (int j = 0; j < 4; ++j) {
        int r = row0 + wm + m * 16 + fq * 4 + j;
        int c = col0 + wn + n * 16 + fr;
        size_t idx = (size_t)r * NB + c;
        float U = u[idx], W = w[idx];
        float S = aS[m][n][j], T = aT[m][n][j];
        pq[idx] = (bf16_t)(U * S + W * T + bias_p[c]);
        pq[SZ + idx] = (bf16_t)(W * S - U * T + bias_q[c]);
      }
}

// ---------------- stage 2: rotation pipeline, 2 blocks/CU ----------------
// out_z = pq_z @ W_z^T + b_z (f32). Tile 128x128, 4 waves (2x2, wave 64x64),
// ring-4 (64 KB -> 2 blocks/CU). Per wave per half: 8 ds_read (next half) +
// 4 gload_lds + 16 MFMA, 1 sync. Grid 512, XCD-swizzled.
__global__ __launch_bounds__(256, 2) void gemm2_v8(
    const bf16_t* __restrict__ pq, const bf16_t* __restrict__ Wpb,
    const bf16_t* __restrict__ Wqb, const float* __restrict__ bp,
    const float* __restrict__ bq, float* __restrict__ out) {
  __shared__ bf16_t lds[4][2][128 * 32];  // [slot][A/W] = 64 KB
  const int tid = threadIdx.x, lane = tid & 63, wv = tid >> 6;
  const int bid = blockIdx.x;
  const int t = (bid & 7) * 64 + (bid >> 3);  // XCD swizzle, 512 blocks
  const int z = t >> 8;
  const int s = t & 255;
  const int row0 = (s & 7) * 128, col0 = (s >> 3) * 128;

  const bf16_t* A = pq + (size_t)z * SZ;
  const bf16_t* Wm = z ? Wqb : Wpb;
  const float* bias = z ? bq : bp;
  float* C = out + (size_t)z * SZ;

  const int wm = (wv >> 1) * 64, wn = (wv & 1) * 64;
  const int lr = lane & 15, kq = lane >> 4;
  const int kswz = (kq ^ ((lr >> 1) & 3)) << 3;

  const int srow = tid >> 2;  // 0..63
  const int sc = (tid & 3) ^ ((tid >> 3) & 3);
  const bf16_t* gA0 = A + (size_t)(row0 + srow) * NB + sc * 8;
  const bf16_t* gA1 = gA0 + (size_t)64 * NB;
  const bf16_t* gW0 = Wm + (size_t)(col0 + srow) * NB + sc * 8;
  const bf16_t* gW1 = gW0 + (size_t)64 * NB;

#define G2_ISSUE(hh)                                                           \
  do {                                                                         \
    const int _sl = (hh) & 3;                                                  \
    const int _ko = (hh) * 32;                                                 \
    GLOAD16(gA0 + _ko, &lds[_sl][0][wv * 512]);                                \
    GLOAD16(gA1 + _ko, &lds[_sl][0][2048 + wv * 512]);                         \
    GLOAD16(gW0 + _ko, &lds[_sl][1][wv * 512]);                                \
    GLOAD16(gW1 + _ko, &lds[_sl][1][2048 + wv * 512]);                         \
  } while (0)

  int aoff[4], woff[4];
#pragma unroll
  for (int m = 0; m < 4; ++m) aoff[m] = (wm + m * 16 + lr) * 32 + kswz;
#pragma unroll
  for (int n = 0; n < 4; ++n) woff[n] = (wn + n * 16 + lr) * 32 + kswz;

#define G2_READ(F, sl)                                                         \
  do {                                                                         \
    const bf16_t* _b = &lds[sl][0][0];                                         \
    _Pragma("unroll") for (int _m = 0; _m < 4; ++_m)                           \
        (F).av[_m] = *reinterpret_cast<const bf16x8*>(_b + aoff[_m]);          \
    _Pragma("unroll") for (int _n = 0; _n < 4; ++_n)                           \
        (F).bw[_n] = *reinterpret_cast<const bf16x8*>(_b + 4096 + woff[_n]);   \
  } while (0)

#define G2_MFMA(F)                                                             \
  do {                                                                         \
    _Pragma("unroll") for (int _m = 0; _m < 4; ++_m)                           \
        _Pragma("unroll") for (int _n = 0; _n < 4; ++_n)                       \
            acc[_m][_n] = MFMA16((F).av[_m], (F).bw[_n], acc[_m][_n]);         \
  } while (0)

  f32x4 acc[4][4] = {};
  G2Frag fA, fB;

  G2_ISSUE(0); G2_ISSUE(1); G2_ISSUE(2);
  VMCNT4();
  SBAR();
  SCHEDB();
  G2_READ(fA, 0);

  for (int h = 0; h < 127; h += 2) {
    G2_READ(fB, (h + 1) & 3);
    if (h + 3 < 128) G2_ISSUE(h + 3);
    G2_MFMA(fA);
    F1_SYNC(h);
    const int h1 = h + 1;
    if (h1 < 127) {
      G2_READ(fA, (h1 + 1) & 3);
      if (h1 + 3 < 128) G2_ISSUE(h1 + 3);
      G2_MFMA(fB);
      F1_SYNC(h1);
    }
  }
  G2_MFMA(fB);

  const int fr = lane & 15, fq = kq;
#pragma unroll
  for (int m = 0; m < 4; ++m)
#pragma unroll
    for (int n = 0; n < 4; ++n)
#pragma unroll
      for (int j = 0; j < 4; ++j) {
        int r = row0 + wm + m * 16 + fq * 4 + j;
        int c = col0 + wn + n * 16 + fr;
        C[(size_t)r * NB + c] = acc[m][n][j] + bias[c];
      }
}

// ---------------- fallbacks (compile-only safety net) ----------------
__device__ __forceinline__ int swz_off32(int r, int kk) {
  return r * 32 + ((kk ^ ((r >> 1) & 3)) << 3);
}

__device__ __forceinline__ void fb_stage_f32(const float* __restrict__ src,
                                             int row0, int k0, bf16_t* lds, int t) {
  int r = t >> 2, kk = t & 3;
  const float* p = src + (size_t)(row0 + r) * NB + k0 + (kk << 3);
  float4 v0 = *reinterpret_cast<const float4*>(p);
  float4 v1 = *reinterpret_cast<const float4*>(p + 4);
  *reinterpret_cast<bf16x8*>(lds + swz_off32(r, kk)) = cvt8(v0, v1);
}

__global__ __launch_bounds__(256, 2) void fb_gemm2(
    const bf16_t* __restrict__ pq, const float* __restrict__ Wp,
    const float* __restrict__ Wq, const float* __restrict__ bp,
    const float* __restrict__ bq, float* __restrict__ out) {
  __shared__ bf16_t lA[128 * 32], lW[128 * 32];
  const int z = blockIdx.z;
  const bf16_t* A = pq + (size_t)z * SZ;
  const float* Wm = z ? Wq : Wp;
  const float* bias = z ? bq : bp;
  float* C = out + (size_t)z * SZ;
  const int tid = threadIdx.x;
  const int lane = tid & 63, wv = tid >> 6;
  const int wm = (wv >> 1) * 64, wn = (wv & 1) * 64;
  const int row0 = blockIdx.y * 128, col0 = blockIdx.x * 128;
  const int lr = lane & 15, kq = lane >> 4;
  const int fslot = (kq ^ ((lr >> 1) & 3)) << 3;
  f32x4 acc[4][4] = {};
  for (int kt = 0; kt < NB; kt += 32) {
#pragma unroll
    for (int p = 0; p < 2; ++p) {
      int cb = p * 256 + wv * 64;
      int ci = cb + lane;
      int r = ci >> 2, kl = ci & 3;
      int ks = kl ^ ((r >> 1) & 3);
      const bf16_t* g = A + (size_t)(row0 + r) * NB + kt + (ks << 3);
      GLOAD16(g, lA + cb * 8);
    }
#pragma unroll
    for (int p = 0; p < 2; ++p)
      fb_stage_f32(Wm, col0, kt, lW, p * 256 + tid);
    __syncthreads();
    bf16x8 af[4], bg[4];
#pragma unroll
    for (int m = 0; m < 4; ++m)
      af[m] = *reinterpret_cast<const bf16x8*>(lA + (wm + m * 16 + lr) * 32 + fslot);
#pragma unroll
    for (int n = 0; n < 4; ++n)
      bg[n] = *reinterpret_cast<const bf16x8*>(lW + (wn + n * 16 + lr) * 32 + fslot);
#pragma unroll
    for (int m = 0; m < 4; ++m)
#pragma unroll
      for (int n = 0; n < 4; ++n)
        acc[m][n] = MFMA16(af[m], bg[n], acc[m][n]);
    __syncthreads();
  }
  const int fr = lane & 15, fq = lane >> 4;
#pragma unroll
  for (int m = 0; m < 4; ++m)
#pragma unroll
    for (int n = 0; n < 4; ++n)
#pragma unroll
      for (int j = 0; j < 4; ++j) {
        int r = row0 + wm + m * 16 + fq * 4 + j;
        int c = col0 + wn + n * 16 + fr;
        C[(size_t)r * NB + c] = acc[m][n][j] + bias[c];
      }
}

__global__ __launch_bounds__(512, 2) void fb_fused1(
    const float* __restrict__ u, const float* __restrict__ w,
    const float* __restrict__ G, const float* __restrict__ Bm,
    const float* __restrict__ bias_p, const float* __restrict__ bias_q,
    bf16_t* __restrict__ pq) {
  __shared__ bf16_t lU[128 * 32], lW[128 * 32], lG[128 * 32], lB[128 * 32];
  const int tid = threadIdx.x;
  const int lane = tid & 63, wv = tid >> 6;
  const int wm = (wv >> 2) * 64, wn = (wv & 3) * 32;
  const int row0 = blockIdx.y * 128, col0 = blockIdx.x * 128;
  const int lr = lane & 15, kq = lane >> 4;
  const int fslot = (kq ^ ((lr >> 1) & 3)) << 3;
  f32x4 aS[4][2] = {}, aT[4][2] = {};
  for (int kt = 0; kt < NB; kt += 32) {
    fb_stage_f32(u, row0, kt, lU, tid);
    fb_stage_f32(w, row0, kt, lW, tid);
    fb_stage_f32(G, col0, kt, lG, tid);
    fb_stage_f32(Bm, col0, kt, lB, tid);
    __syncthreads();
    bf16x8 au[4], aw[4], bG[2], bB[2], bBn[2];
#pragma unroll
    for (int m = 0; m < 4; ++m) {
      int off = (wm + m * 16 + lr) * 32 + fslot;
      au[m] = *reinterpret_cast<const bf16x8*>(lU + off);
      aw[m] = *reinterpret_cast<const bf16x8*>(lW + off);
    }
#pragma unroll
    for (int n = 0; n < 2; ++n) {
      int off = (wn + n * 16 + lr) * 32 + fslot;
      bG[n] = *reinterpret_cast<const bf16x8*>(lG + off);
      bB[n] = *reinterpret_cast<const bf16x8*>(lB + off);
      bBn[n] = neg8(bB[n]);
    }
#pragma unroll
    for (int m = 0; m < 4; ++m)
#pragma unroll
      for (int n = 0; n < 2; ++n) {
        aS[m][n] = MFMA16(au[m], bG[n], aS[m][n]);
        aS[m][n] = MFMA16(aw[m], bBn[n], aS[m][n]);
        aT[m][n] = MFMA16(aw[m], bG[n], aT[m][n]);
        aT[m][n] = MFMA16(au[m], bB[n], aT[m][n]);
      }
    __syncthreads();
  }
  const int fr = lane & 15, fq = lane >> 4;
#pragma unroll
  for (int m = 0; m < 4; ++m)
#pragma unroll
    for (int n = 0; n < 2; ++n)
#pragma unroll
      for (int j = 0; j < 4; ++j) {
        int r = row0 + wm + m * 16 + fq * 4 + j;
        int c = col0 + wn + n * 16 + fr;
        size_t idx = (size_t)r * NB + c;
        float U = u[idx], W = w[idx];
        float S = aS[m][n][j], T = aT[m][n][j];
        pq[idx] = (bf16_t)(U * S + W * T + bias_p[c]);
        pq[SZ + idx] = (bf16_t)(W * S - U * T + bias_q[c]);
      }
}

extern "C" void kernel_launch(void* const* d_in, const int* in_sizes, int n_in,
                              void* d_out, int out_size, void* d_ws, size_t ws_size,
                              hipStream_t stream) {
  const float* u = (const float*)d_in[0];
  const float* w = (const float*)d_in[1];
  const float* G = (const float*)d_in[2];
  const float* Bm = (const float*)d_in[3];
  const float* bias_p = (const float*)d_in[4];
  const float* bias_q = (const float*)d_in[5];
  const float* Wp = (const float*)d_in[6];
  const float* bp = (const float*)d_in[7];
  const float* Wq = (const float*)d_in[8];
  const float* bq = (const float*)d_in[9];
  (void)in_sizes; (void)n_in; (void)out_size;

  const size_t need_full = (6 * SZ + 4 * NN) * sizeof(bf16_t);  // 176 MB
  const size_t need_mid = (6 * SZ + 2 * NN) * sizeof(bf16_t);   // 112 MB

  if (ws_size >= need_full) {
    bf16_t* ws = (bf16_t*)d_ws;
    bf16_t* ubf = ws;
    bf16_t* wbf = ws + SZ;
    bf16_t* Gbf = ws + 2 * SZ;
    bf16_t* Bbf = Gbf + NN;
    bf16_t* Wpb = Bbf + NN;
    bf16_t* Wqb = Wpb + NN;
    bf16_t* pqw = Wqb + NN;
    prep6_kernel<<<2048, 256, 0, stream>>>(u, w, G, Bm, Wp, Wq, ws);
    fused1_v7<<<256, 512, 0, stream>>>(u, w, ubf, wbf, Gbf, Bbf,
                                       bias_p, bias_q, pqw);
    gemm2_v8<<<512, 256, 0, stream>>>(pqw, Wpb, Wqb, bp, bq, (float*)d_out);
  } else if (ws_size >= need_mid) {
    bf16_t* ws = (bf16_t*)d_ws;
    bf16_t* ubf = ws;
    bf16_t* wbf = ws + SZ;
    bf16_t* Gbf = ws + 2 * SZ;
    bf16_t* Bbf = Gbf + NN;
    bf16_t* pqw = Bbf + NN;
    prep4_kernel<<<2048, 256, 0, stream>>>(u, w, G, Bm, ws);
    fused1_v7<<<256, 512, 0, stream>>>(u, w, ubf, wbf, Gbf, Bbf,
                                       bias_p, bias_q, pqw);
    fb_gemm2<<<dim3(NB / 128, MB / 128, 2), 256, 0, stream>>>(
        pqw, Wp, Wq, bp, bq, (float*)d_out);
  } else {
    bf16_t* pqw = (bf16_t*)d_ws;
    fb_fused1<<<dim3(NB / 128, MB / 128), 512, 0, stream>>>(
        u, w, G, Bm, bias_p, bias_q, pqw);
    fb_gemm2<<<dim3(NB / 128, MB / 128, 2), 256, 0, stream>>>(
        pqw, Wp, Wq, bp, bq, (float*)d_out);
  }
}